// Round 4
// baseline (3133.960 us; speedup 1.0000x reference)
//
#include <hip/hip_runtime.h>

#define T_SZ 12
#define NSTEP 2
#define R_WG 16
#define NTHR 256
#define NWG  512   // 8192 / R_WG

typedef const __attribute__((address_space(1))) void* gas1_t;
typedef __attribute__((address_space(3))) void* las3_t;

__device__ __forceinline__ void gload16(const void* g, void* l){
  __builtin_amdgcn_global_load_lds((gas1_t)g, (las3_t)l, 16, 0, 0);
}

__device__ __forceinline__ float sigm(float x){ return 1.f/(1.f + __expf(-x)); }
__device__ __forceinline__ float tanh_f(float x){
  float e = __expf(-2.f*fabsf(x));
  float t = (1.f - e)/(1.f + e);
  return x < 0.f ? -t : t;
}

// stage one 16-k-row weight chunk (1024 float4) into LDS: linear, lane x 16B
__device__ __forceinline__ void issue_chunk(const float4* gsrc, float* lbuf, int tid){
  const int wv = tid>>6, ln = tid&63;
  #pragma unroll
  for (int j=0;j<4;j++){
    int idx = j*256 + wv*64;               // wave-uniform float4 index
    gload16(gsrc + idx + ln, (float4*)lbuf + idx);
  }
}

// stage 16 rows x 16 floats of x into tsb (one wave: 64 lanes = 64 float4)
__device__ __forceinline__ void issue_xin(const float* gsrc, int rowstride_f4, float* tsb, int ln){
  int r = ln>>2, q = ln&3;
  gload16((const float4*)gsrc + (size_t)r*rowstride_f4 + q, tsb);
}

// a[ri*4+g] += sum_{c<4} x[row][k+c] * W[k+c][u][g]   (W chunk in LDS, x broadcast)
__device__ __forceinline__ void gemm_k4(float a[16], const float4* wb, int kk, int u,
                                        const float* xbase, int xstride, int xoff, int rbase){
  float4 wv0 = wb[(kk+0)*64+u], wv1 = wb[(kk+1)*64+u];
  float4 wv2 = wb[(kk+2)*64+u], wv3 = wb[(kk+3)*64+u];
  #pragma unroll
  for (int ri=0; ri<4; ri++){
    float4 xv = *(const float4*)(xbase + (rbase+ri)*xstride + xoff);
    a[ri*4+0] += xv.x*wv0.x + xv.y*wv1.x + xv.z*wv2.x + xv.w*wv3.x;
    a[ri*4+1] += xv.x*wv0.y + xv.y*wv1.y + xv.z*wv2.y + xv.w*wv3.y;
    a[ri*4+2] += xv.x*wv0.z + xv.y*wv1.z + xv.z*wv2.z + xv.w*wv3.z;
    a[ri*4+3] += xv.x*wv0.w + xv.y*wv1.w + xv.z*wv2.w + xv.w*wv3.w;
  }
}

// out[r][u] = act( sum_k x[r][k] * Wg[u][k] + bias[u] (+out) ), weights row-major, direct global
__device__ __forceinline__ void sgemm_row(float* out, int ostride, const float* x, int xstride,
                                          const float* Wg, int wstride, const float* bias,
                                          bool add, bool relu, int u, int rbase){
  const float* wrow = Wg + (size_t)u*wstride;
  float acc[4] = {0.f,0.f,0.f,0.f};
  #pragma unroll
  for (int k=0;k<64;k+=4){
    float4 wv = *(const float4*)(wrow + k);
    #pragma unroll
    for (int ri=0;ri<4;ri++){
      float4 xv = *(const float4*)(x + (rbase+ri)*xstride + k);
      acc[ri] += xv.x*wv.x + xv.y*wv.y + xv.z*wv.z + xv.w*wv.w;
    }
  }
  float b = bias ? bias[u] : 0.f;
  #pragma unroll
  for (int ri=0;ri<4;ri++){
    int idx = (rbase+ri)*ostride + u;
    float v = acc[ri] + b;
    if (add)  v += out[idx];
    if (relu) v = fmaxf(v, 0.f);
    out[idx] = v;
  }
}

// out[r][u] = sum_k x[r][k] * Wg[k][u]   (column access, coalesced across lanes)
__device__ __forceinline__ void sgemm_col(float* out, const float* x, const float* Wg,
                                          int u, int rbase){
  float acc[4] = {0.f,0.f,0.f,0.f};
  #pragma unroll
  for (int k=0;k<64;k+=4){
    float w0=Wg[(k+0)*64+u], w1=Wg[(k+1)*64+u], w2=Wg[(k+2)*64+u], w3=Wg[(k+3)*64+u];
    #pragma unroll
    for (int ri=0;ri<4;ri++){
      float4 xv = *(const float4*)(x + (rbase+ri)*64 + k);
      acc[ri] += xv.x*w0 + xv.y*w1 + xv.z*w2 + xv.w*w3;
    }
  }
  #pragma unroll
  for (int ri=0;ri<4;ri++) out[(rbase+ri)*64+u] = acc[ri];
}

struct Ptrs {
  const float* ts; const float* gts;
  const float* W4ts; const float* b4ts;
  const float* W4nd; const float* b4nd;
  const float* Qw; const float* Qb; const float* Kw;
  const float* Vw; const float* Vb; const float* Fw; const float* Fb;
  const float* f1w; const float* f1b;
  const float* m1w; const float* m1b; const float* m2w; const float* m2b;
  float* cg; float* g_hn; float* g_hta; float* g_cts; float* out;
};

__global__ __launch_bounds__(NTHR, 2) void fused_step(Ptrs P, int t0){
  __shared__ __align__(16) float bufA[4096];    // 16 KB chunk buffer / attn tmps
  __shared__ __align__(16) float bufB[4096];    // 16 KB chunk buffer / final hid
  __shared__ __align__(16) float h_node[8192];  // 32 KB: [r][n][64]
  __shared__ __align__(16) float h_ts [1024];
  __shared__ __align__(16) float h_tsa[1024];
  __shared__ __align__(16) float tsb  [256];    // [16][16] x-input stage
  __shared__ float pbuf[128];

  const int tid = threadIdx.x;
  const int r0  = blockIdx.x * R_WG;
  const int u = tid&63, wv = tid>>6, ln = tid&63;
  const int rbase = wv*4;
  float* tmpA = bufA;            // aliases: live only during attention/fusion
  float* tmpB = bufA + 1024;

  float c_ts[4];

  // ---- entry: restore (or init) persistent state ----
  if (t0 == 0){
    for (int i=tid;i<8192;i+=NTHR) h_node[i]=0.f;
    for (int i=tid;i<1024;i+=NTHR) h_tsa[i]=0.f;
    #pragma unroll
    for (int ri=0;ri<4;ri++) c_ts[ri]=0.f;
  } else {
    for (int i=tid;i<8192;i+=NTHR) h_node[i]=P.g_hn[(size_t)r0*512+i];
    for (int i=tid;i<1024;i+=NTHR) h_tsa[i]=P.g_hta[(size_t)r0*64+i];
    #pragma unroll
    for (int ri=0;ri<4;ri++) c_ts[ri]=P.g_cts[(size_t)(r0+rbase+ri)*64+u];
  }

  for (int tt=0;tt<NSTEP;tt++){
    const int t = t0+tt;
    __syncthreads();   // bufA free; state writes visible
    // ---- prologue: stage A-lstm chunk0 + its x ----
    issue_chunk((const float4*)P.W4ts + (size_t)t*5120, bufA, tid);
    if (wv==0) issue_xin(P.ts + (size_t)r0*192 + t*16, 48, tsb, ln);
    __syncthreads();   // barrier drains vmcnt -> chunk0 + tsb ready
    int p = 0;

    // ---- 9 LSTMs: l=0 is the ts-LSTM, l=1..8 are nodes 0..7 ----
    for (int l=0;l<9;l++){
      const float4* Wcur = (l==0) ? (const float4*)P.W4ts + (size_t)t*5120
                                  : (const float4*)P.W4nd + (size_t)((l-1)*T_SZ+t)*5120;
      const float* hb   = (l==0) ? h_tsa : h_node + (l-1)*64;
      const int hstride = (l==0) ? 64 : 512;
      float a[16];
      #pragma unroll
      for (int i=0;i<16;i++) a[i]=0.f;

      for (int q=0;q<5;q++){
        float* bufc = p ? bufB : bufA;
        float* bufn = p ? bufA : bufB;
        if (q<4){
          issue_chunk(Wcur + (q+1)*1024, bufn, tid);
        } else if (l<8){   // chain: next LSTM's chunk0 + x
          issue_chunk((const float4*)P.W4nd + (size_t)(l*T_SZ+t)*5120, bufn, tid);
          if (wv==0) issue_xin(P.gts + ((size_t)r0*8 + l)*192 + t*16, 384, tsb, ln);
        }
        const float* xb = (q==0) ? tsb : hb;
        const int xs    = (q==0) ? 16  : hstride;
        const int xo    = (q==0) ? 0   : (q-1)*16;
        const float4* wb4 = (const float4*)bufc;
        #pragma unroll
        for (int kk=0;kk<16;kk+=4)
          gemm_k4(a, wb4, kk, u, xb, xs, xo+kk, rbase);
        __syncthreads();   // drains just-issued loads; bufc free for reuse
        p ^= 1;
      }

      // ---- nonlinearity ----
      const float* bias = (l==0) ? P.b4ts + t*256 : P.b4nd + ((l-1)*T_SZ+t)*256;
      float4 bv = *(const float4*)(bias + u*4);
      #pragma unroll
      for (int ri=0;ri<4;ri++){
        float iv = sigm(a[ri*4+0]+bv.x);
        float fv = sigm(a[ri*4+1]+bv.y);
        float gv = tanh_f(a[ri*4+2]+bv.z);
        float ov = sigm(a[ri*4+3]+bv.w);
        float cold;
        if (l==0) cold = c_ts[ri];
        else      cold = (t==0) ? 0.f
                       : P.cg[((size_t)(l-1)*8192 + r0+rbase+ri)*64 + u];
        float c2 = fv*cold + iv*gv;
        float hv = ov*tanh_f(c2);
        if (l==0){ c_ts[ri]=c2; h_ts[(rbase+ri)*64+u]=hv; }
        else { P.cg[((size_t)(l-1)*8192 + r0+rbase+ri)*64 + u] = c2;
               h_node[((rbase+ri)*8+(l-1))*64+u] = hv; }
      }
    }
    __syncthreads();   // all h writes visible

    // ---- attention (weights direct from global, L2-resident) ----
    sgemm_row(tmpA, 64, h_ts, 64, P.Qw, 64, P.Qb, false, false, u, rbase);   // q
    __syncthreads();
    sgemm_col(tmpB, tmpA, P.Kw, u, rbase);                                   // qk = q @ Kw
    __syncthreads();
    if (tid < 128){   // scores + softmax over n
      int r=tid>>3, n=tid&7, lane=tid&63;
      float s=0.f;
      for (int c0=0;c0<64;c0++){
        int c=(c0+lane)&63;
        s += h_node[(r*8+n)*64+c]*tmpB[r*64+c];
      }
      s *= 0.125f;
      float mx=s;
      mx=fmaxf(mx,__shfl_xor(mx,1,8));
      mx=fmaxf(mx,__shfl_xor(mx,2,8));
      mx=fmaxf(mx,__shfl_xor(mx,4,8));
      float e=__expf(s-mx);
      float sm=e;
      sm+=__shfl_xor(sm,1,8); sm+=__shfl_xor(sm,2,8); sm+=__shfl_xor(sm,4,8);
      pbuf[tid]=e/sm;
    }
    __syncthreads();
    { // hbar = sum_n p_n h_node[n] -> tmpA (q dead)
      #pragma unroll
      for (int ri=0;ri<4;ri++){
        int r=rbase+ri;
        float sacc=0.f;
        #pragma unroll
        for (int n=0;n<8;n++) sacc += pbuf[r*8+n]*h_node[(r*8+n)*64+u];
        tmpA[r*64+u]=sacc;
      }
    }
    __syncthreads();
    sgemm_row(tmpB, 64, tmpA, 64, P.Vw, 64, P.Vb, false, false, u, rbase);   // ctx
    __syncthreads();
    sgemm_row(h_tsa, 64, tmpB, 64, P.Fw,    128, P.Fb, false, false, u, rbase); // ctx part
    sgemm_row(h_tsa, 64, h_ts, 64, P.Fw+64, 128, nullptr, true, true, u, rbase); // + query, relu
    __syncthreads();   // tmpA readers (ctx) done before overwrite
    sgemm_row(tmpA, 64, h_ts, 64, P.f1w+64, 128, P.f1b, false, false, u, rbase); // f_ts

    // ---- fusion over 8 nodes, register-light (acc[4] per node) ----
    {
      const float* wrow_f = P.f1w + (size_t)u*128;   // cols 0..63
      #pragma unroll 1
      for (int n=0;n<8;n++){
        float acc0=0.f, acc1=0.f, acc2=0.f, acc3=0.f;
        #pragma unroll 4
        for (int k=0;k<64;k+=4){
          float4 wvv = *(const float4*)(wrow_f + k);
          float4 x0 = *(const float4*)(h_node + ((rbase+0)*8+n)*64 + k);
          float4 x1 = *(const float4*)(h_node + ((rbase+1)*8+n)*64 + k);
          float4 x2 = *(const float4*)(h_node + ((rbase+2)*8+n)*64 + k);
          float4 x3 = *(const float4*)(h_node + ((rbase+3)*8+n)*64 + k);
          acc0 += x0.x*wvv.x + x0.y*wvv.y + x0.z*wvv.z + x0.w*wvv.w;
          acc1 += x1.x*wvv.x + x1.y*wvv.y + x1.z*wvv.z + x1.w*wvv.w;
          acc2 += x2.x*wvv.x + x2.y*wvv.y + x2.z*wvv.z + x2.w*wvv.w;
          acc3 += x3.x*wvv.x + x3.y*wvv.y + x3.z*wvv.z + x3.w*wvv.w;
        }
        __syncthreads();   // all reads of node-n slice done before its overwrite
        float accs[4]={acc0,acc1,acc2,acc3};
        #pragma unroll
        for (int ri=0;ri<4;ri++){
          float v = accs[ri] + tmpA[(rbase+ri)*64+u];   // own elements
          h_node[((rbase+ri)*8+n)*64+u] = fmaxf(v,0.f);
        }
      }
    }
  }
  __syncthreads();

  if (t0 + NSTEP >= T_SZ){
    // ---- final MLP: out = relu(h_tsa@m1.T + b1) @ m2.T + b2 ----
    float* hidb = bufB;          // 16 rows x 32
    int r = tid>>4, i2 = tid&15;
    #pragma unroll
    for (int jj=0;jj<2;jj++){
      int i = i2 + jj*16;
      float hsum = P.m1b[i];
      #pragma unroll
      for (int k=0;k<64;k+=4){
        float4 wvv = *(const float4*)(P.m1w + (size_t)i*64 + k);
        float4 xv  = *(const float4*)(h_tsa + r*64 + k);
        hsum += xv.x*wvv.x + xv.y*wvv.y + xv.z*wvv.z + xv.w*wvv.w;
      }
      hidb[r*32+i] = fmaxf(hsum, 0.f);
    }
    __syncthreads();
    if (tid < R_WG){
      float s = P.m2b[0];
      for (int i=0;i<32;i++) s += hidb[tid*32+i]*P.m2w[i];
      P.out[r0+tid] = s;
    }
  } else {
    // ---- exit: persist state ----
    for (int i=tid;i<8192;i+=NTHR) P.g_hn[(size_t)r0*512+i]=h_node[i];
    for (int i=tid;i<1024;i+=NTHR) P.g_hta[(size_t)r0*64+i]=h_tsa[i];
    #pragma unroll
    for (int ri=0;ri<4;ri++) P.g_cts[(size_t)(r0+rbase+ri)*64+u]=c_ts[ri];
  }
}

// ---- prep: fold embedding into Wih; layout [l][k][u][4gates], biases [l][u][4] ----
__global__ void prep_w_kernel(const float* Wih, const float* Whh, const float* emb_w,
                              float* dst, int L){
  int idx = blockIdx.x*256 + threadIdx.x;
  int total = L*80*64;
  if (idx >= total) return;
  int l = idx / (80*64);
  int rem = idx % (80*64);
  int k = rem / 64;
  int u = rem & 63;
  float v[4];
  if (k < 16){
    #pragma unroll
    for (int g=0;g<4;g++){
      int j = g*64+u;
      float s = 0.f;
      for (int i=0;i<32;i++) s += Wih[((size_t)l*256+j)*32+i]*emb_w[i*16+k];
      v[g]=s;
    }
  } else {
    #pragma unroll
    for (int g=0;g<4;g++) v[g]=Whh[((size_t)l*256+g*64+u)*64+(k-16)];
  }
  float* d = dst + (size_t)l*20480 + k*256 + u*4;
  d[0]=v[0]; d[1]=v[1]; d[2]=v[2]; d[3]=v[3];
}

__global__ void prep_b_kernel(const float* bih, const float* bhh, const float* Wih,
                              const float* emb_b, float* dst, int L){
  int idx = blockIdx.x*256 + threadIdx.x;
  if (idx >= L*64) return;
  int l = idx/64, u = idx&63;
  #pragma unroll
  for (int g=0;g<4;g++){
    int j=g*64+u;
    float s = bih[l*256+j] + bhh[l*256+j];
    for (int i=0;i<32;i++) s += Wih[((size_t)l*256+j)*32+i]*emb_b[i];
    dst[l*256 + u*4 + g] = s;
  }
}

extern "C" void kernel_launch(void* const* d_in, const int* in_sizes, int n_in,
                              void* d_out, int out_size, void* d_ws, size_t ws_size,
                              hipStream_t stream){
  const float* ts      = (const float*)d_in[0];
  const float* gts     = (const float*)d_in[1];
  const float* emb_w   = (const float*)d_in[2];
  const float* emb_b   = (const float*)d_in[3];
  const float* attQ_w  = (const float*)d_in[4];
  const float* attQ_b  = (const float*)d_in[5];
  const float* attK_w  = (const float*)d_in[6];
  // d_in[7] = attK_b : constant shift under softmax, unused
  const float* attV_w  = (const float*)d_in[8];
  const float* attV_b  = (const float*)d_in[9];
  const float* attF_w  = (const float*)d_in[10];
  const float* attF_b  = (const float*)d_in[11];
  const float* fuse1_w = (const float*)d_in[12];
  const float* fuse1_b = (const float*)d_in[13];
  const float* enc_Wih = (const float*)d_in[14];
  const float* enc_Whh = (const float*)d_in[15];
  const float* enc_bih = (const float*)d_in[16];
  const float* enc_bhh = (const float*)d_in[17];
  const float* enc2_Wih= (const float*)d_in[18];
  const float* enc2_Whh= (const float*)d_in[19];
  const float* enc2_bih= (const float*)d_in[20];
  const float* enc2_bhh= (const float*)d_in[21];
  const float* mlp1_w  = (const float*)d_in[22];
  const float* mlp1_b  = (const float*)d_in[23];
  const float* mlp2_w  = (const float*)d_in[24];
  const float* mlp2_b  = (const float*)d_in[25];

  float* ws = (float*)d_ws;
  size_t off = 0;
  float* W4ts = ws + off; off += 12*20480;
  float* b4ts = ws + off; off += 12*256;
  float* W4nd = ws + off; off += (size_t)96*20480;
  float* b4nd = ws + off; off += 96*256;
  float* cg   = ws + off; off += (size_t)8*8192*64;
  float* g_hn = ws + off; off += (size_t)8192*512;
  float* g_hta= ws + off; off += (size_t)8192*64;
  float* g_cts= ws + off; off += (size_t)8192*64;

  prep_w_kernel<<<(12*80*64+255)/256, 256, 0, stream>>>(enc_Wih, enc_Whh, emb_w, W4ts, 12);
  prep_w_kernel<<<(96*80*64+255)/256, 256, 0, stream>>>(enc2_Wih, enc2_Whh, emb_w, W4nd, 96);
  prep_b_kernel<<<(12*64+255)/256, 256, 0, stream>>>(enc_bih, enc_bhh, enc_Wih, emb_b, b4ts, 12);
  prep_b_kernel<<<(96*64+255)/256, 256, 0, stream>>>(enc2_bih, enc2_bhh, enc2_Wih, emb_b, b4nd, 96);

  Ptrs P;
  P.ts=ts; P.gts=gts; P.W4ts=W4ts; P.b4ts=b4ts; P.W4nd=W4nd; P.b4nd=b4nd;
  P.Qw=attQ_w; P.Qb=attQ_b; P.Kw=attK_w;
  P.Vw=attV_w; P.Vb=attV_b; P.Fw=attF_w; P.Fb=attF_b;
  P.f1w=fuse1_w; P.f1b=fuse1_b;
  P.m1w=mlp1_w; P.m1b=mlp1_b; P.m2w=mlp2_w; P.m2b=mlp2_b;
  P.cg=cg; P.g_hn=g_hn; P.g_hta=g_hta; P.g_cts=g_cts; P.out=(float*)d_out;

  for (int t0=0; t0<T_SZ; t0+=NSTEP)
    fused_step<<<NWG, NTHR, 0, stream>>>(P, t0);
}

// Round 5
// 2591.412 us; speedup vs baseline: 1.2094x; 1.2094x over previous
//
#include <hip/hip_runtime.h>

#define T_SZ 12
#define R_WG 16
#define NTHR 256
#define NWG  512   // 8192 / R_WG

typedef float vf4 __attribute__((ext_vector_type(4)));
typedef int   vi4 __attribute__((ext_vector_type(4)));
typedef const __attribute__((address_space(1))) void* gas1_t;
typedef __attribute__((address_space(3))) void* las3_t;

__device__ __forceinline__ void gload16(const void* g, void* l){
  __builtin_amdgcn_global_load_lds((gas1_t)g,(las3_t)l,16,0,0);
}
__device__ __forceinline__ float sigm(float x){ return 1.f/(1.f+__expf(-x)); }
__device__ __forceinline__ float tanh_f(float x){
  float e=__expf(-2.f*fabsf(x)); float t=(1.f-e)/(1.f+e); return x<0.f?-t:t;
}
__device__ __forceinline__ unsigned short bf_hi(float f){
  unsigned int b=__float_as_uint(f);
  return (unsigned short)((b + 0x7fffu + ((b>>16)&1u))>>16);
}
__device__ __forceinline__ float bf_f(unsigned short h){
  return __uint_as_float(((unsigned int)h)<<16);
}

// D = A(16x32 bf16) * B(32x16 bf16) + C ; A: row=lane&15,k=8*(lane>>4)+j ; B: col=lane&15 same k
__device__ __forceinline__ vf4 mfma16(vi4 a, vi4 b, vf4 c){
  asm("v_mfma_f32_16x16x32_bf16 %0, %1, %2, %0" : "+v"(c) : "v"(a), "v"(b));
  return c;
}

// stage one 16 KB chunk (1024 x 16B), linear, wave-uniform LDS base
__device__ __forceinline__ void issue_chunk16(const char* gsrc, char* lds, int tid){
  const int wv=tid>>6, ln=tid&63;
  #pragma unroll
  for(int j=0;j<4;j++){
    int off=(j*256+wv*64)*16;
    gload16(gsrc+off+ln*16, lds+off);
  }
}

// h9 split-bf16 storage: [slot(9)][s(2)][row(16)][blk(8)][16B], blk swizzled ^ (row&7)
__device__ __forceinline__ int h9_blkoff(int slot,int s,int row,int blk){
  return (((slot*2+s)*16+row)*8+blk)*16;
}
__device__ __forceinline__ int h9_off(int slot,int s,int row,int k){
  int blk=(k>>3)^(row&7);
  return h9_blkoff(slot,s,row,blk)+(k&7)*2;
}
__device__ __forceinline__ float h9_read(const char* h9,int slot,int row,int k){
  return bf_f(*(const unsigned short*)(h9+h9_off(slot,0,row,k)))
       + bf_f(*(const unsigned short*)(h9+h9_off(slot,1,row,k)));
}

struct Ptrs {
  const float* ts; const float* gts;
  const unsigned short* Wm;            // MFMA weight chunks
  const float* b4ts; const float* b4nd;
  const float* Qt; const float* Qb; const float* Kw;
  const float* VFt; const float* FBt; const float* Fbp;
  const float* F1At; const float* F1Bt; const float* f1b;
  const float* m1w; const float* m1b; const float* m2w; const float* m2b;
  float* cg; float* out;
};

__global__ __launch_bounds__(NTHR,2) void fused_kernel(Ptrs P){
  __shared__ __align__(16) float bufs[8192];     // 2 x 16KB chunk bufs; hrec during attention
  __shared__ __align__(16) char  h9[36864];      // 9 slots split-bf16 h (slot0 = h_tsa)
  __shared__ __align__(16) float h_ts[1024];     // fp32 h_ts
  __shared__ __align__(16) float attn_s[1024];   // qk / hbar / f_ts

  const int tid=threadIdx.x, wv=tid>>6, ln=tid&63;
  const int r0=blockIdx.x*R_WG;
  const int arow=ln&15, kb=ln>>4;                 // A-frag row / k-block
  const int gt=ln&3;
  float* qbuf=(float*)h9;                         // slot0 region doubles as q / pbuf scratch

  for(int i=tid;i<9216;i+=NTHR) ((float*)h9)[i]=0.f;

  for(int t=0;t<T_SZ;t++){
    // t-head: stage chunk0 of l=0 (bufs free; zeros/fusion visible after barrier)
    issue_chunk16((const char*)P.Wm + (size_t)(0*12+t)*6*16384, (char*)bufs, tid);
    __syncthreads();
    int p=0;

    for(int l=0;l<9;l++){
      const size_t lbase=(size_t)(l*12+t)*6*16384;
      // x inputs -> regs (consumed at ks==2; latency hides under chunks 0..3)
      vf4 x0={0.f,0.f,0.f,0.f}, x1={0.f,0.f,0.f,0.f};
      if(kb<2){
        const float* xs=(l==0)? P.ts + (size_t)(r0+arow)*192 + t*16 + kb*8
                              : P.gts + ((size_t)(r0+arow)*8 + (l-1))*192 + t*16 + kb*8;
        x0=*(const vf4*)xs; x1=*(const vf4*)(xs+4);
      }
      vf4 acc[4];
      #pragma unroll
      for(int nt=0;nt<4;nt++) acc[nt]=(vf4){0.f,0.f,0.f,0.f};
      vi4 Ah,Al;

      for(int ks=0;ks<3;ks++){
        // ---- hi chunk (cc=ks*2) resident in buf[p]; issue lo chunk ----
        issue_chunk16((const char*)P.Wm + lbase + (size_t)(ks*2+1)*16384,
                      (char*)bufs + (p^1)*16384, tid);
        if(ks==2){
          unsigned short hh[8],ll[8];
          float xf[8]={x0[0],x0[1],x0[2],x0[3],x1[0],x1[1],x1[2],x1[3]};
          #pragma unroll
          for(int j=0;j<8;j++){ hh[j]=bf_hi(xf[j]); ll[j]=bf_hi(xf[j]-bf_f(hh[j])); }
          Ah=(vi4){(int)(hh[0]|(hh[1]<<16)),(int)(hh[2]|(hh[3]<<16)),
                   (int)(hh[4]|(hh[5]<<16)),(int)(hh[6]|(hh[7]<<16))};
          Al=(vi4){(int)(ll[0]|(ll[1]<<16)),(int)(ll[2]|(ll[3]<<16)),
                   (int)(ll[4]|(ll[5]<<16)),(int)(ll[6]|(ll[7]<<16))};
        } else {
          int blk=(ks*4+kb)^(arow&7);
          Ah=*(const vi4*)(h9+h9_blkoff(l,0,arow,blk));
          Al=*(const vi4*)(h9+h9_blkoff(l,1,arow,blk));
        }
        const vi4* bb=(const vi4*)((const char*)bufs + p*16384);
        #pragma unroll
        for(int nt=0;nt<4;nt++){
          vi4 B=bb[(wv*4+nt)*64+ln];
          acc[nt]=mfma16(Ah,B,acc[nt]);
          acc[nt]=mfma16(Al,B,acc[nt]);
        }
        __syncthreads();
        p^=1;
        // ---- lo chunk resident; issue next hi (or next l's chunk0) ----
        if(ks<2)      issue_chunk16((const char*)P.Wm + lbase + (size_t)(ks*2+2)*16384,
                                    (char*)bufs + (p^1)*16384, tid);
        else if(l<8)  issue_chunk16((const char*)P.Wm + (size_t)((l+1)*12+t)*6*16384,
                                    (char*)bufs + (p^1)*16384, tid);
        bb=(const vi4*)((const char*)bufs + p*16384);
        #pragma unroll
        for(int nt=0;nt<4;nt++){
          vi4 B=bb[(wv*4+nt)*64+ln];
          acc[nt]=mfma16(Ah,B,acc[nt]);
        }
        __syncthreads();
        p^=1;
      }

      // ---- nonlinearity: gates i,f,g,o live in adjacent lanes (G = u*4+gt) ----
      const float* bias=(l==0)? P.b4ts + t*256 : P.b4nd + ((l-1)*T_SZ+t)*256;
      #pragma unroll
      for(int nt=0;nt<4;nt++){
        int u=wv*16 + nt*4 + ((ln&15)>>2);
        vf4 bv=*(const vf4*)(bias+u*4);
        #pragma unroll
        for(int r=0;r<4;r++){
          float v=acc[nt][r];
          float s1=__shfl_xor(v,1), s2=__shfl_xor(v,2), s3=__shfl_xor(v,3);
          float gi=(gt==0)?v :(gt==1)?s1:(gt==2)?s2:s3;
          float gf=(gt==0)?s1:(gt==1)?v :(gt==2)?s3:s2;
          float gg=(gt==0)?s2:(gt==1)?s3:(gt==2)?v :s1;
          float go=(gt==0)?s3:(gt==1)?s2:(gt==2)?s1:v;
          int row=kb*4+r;
          size_t cidx=((size_t)l*8192 + r0+row)*64 + u;
          float cold=(t==0)?0.f:P.cg[cidx];
          float iv=sigm(gi+bv[0]), fv=sigm(gf+bv[1]);
          float gv=tanh_f(gg+bv[2]), ov=sigm(go+bv[3]);
          float c2=fv*cold+iv*gv;
          float hv=ov*tanh_f(c2);
          if(gt==0) P.cg[cidx]=c2;
          if(l==0){
            if(gt==0) h_ts[row*64+u]=hv;
          } else {
            unsigned short hb=bf_hi(hv);
            if(gt==0) *(unsigned short*)(h9+h9_off(l,0,row,u))=hb;
            if(gt==1) *(unsigned short*)(h9+h9_off(l,1,row,u))=bf_hi(hv-bf_f(hb));
          }
        }
      }
    }
    __syncthreads();   // B1: all h writes visible

    const int u=tid&63, rb=(tid>>6)*4;
    float* hrec=bufs;  // [row][n][64] fp32 reconstruction (chunk bufs idle)

    // hrec build + q (disjoint regions)
    for(int i=tid;i<8192;i+=NTHR){
      int row=i>>9, nn=(i>>6)&7, uu=i&63;
      hrec[i]=h9_read(h9,nn+1,row,uu);
    }
    { // q = h_ts @ Qw.T + Qb   -> qbuf (slot0 region, its data already consumed)
      float a0=0,a1=0,a2=0,a3=0;
      for(int k=0;k<64;k+=4){
        #pragma unroll
        for(int kk=0;kk<4;kk++){
          float w=P.Qt[(k+kk)*64+u];
          a0+=h_ts[(rb+0)*64+k+kk]*w; a1+=h_ts[(rb+1)*64+k+kk]*w;
          a2+=h_ts[(rb+2)*64+k+kk]*w; a3+=h_ts[(rb+3)*64+k+kk]*w;
        }
      }
      float b=P.Qb[u];
      qbuf[(rb+0)*64+u]=a0+b; qbuf[(rb+1)*64+u]=a1+b;
      qbuf[(rb+2)*64+u]=a2+b; qbuf[(rb+3)*64+u]=a3+b;
    }
    __syncthreads();   // B2
    { // qk = q @ Kw -> attn_s
      float a0=0,a1=0,a2=0,a3=0;
      for(int k=0;k<64;k+=4){
        #pragma unroll
        for(int kk=0;kk<4;kk++){
          float w=P.Kw[(k+kk)*64+u];
          a0+=qbuf[(rb+0)*64+k+kk]*w; a1+=qbuf[(rb+1)*64+k+kk]*w;
          a2+=qbuf[(rb+2)*64+k+kk]*w; a3+=qbuf[(rb+3)*64+k+kk]*w;
        }
      }
      attn_s[(rb+0)*64+u]=a0; attn_s[(rb+1)*64+u]=a1;
      attn_s[(rb+2)*64+u]=a2; attn_s[(rb+3)*64+u]=a3;
    }
    __syncthreads();   // B3
    if(tid<128){ // scores + softmax -> qbuf[0..127] (q dead)
      int r=tid>>3, n=tid&7, lane=tid&63;
      float s=0.f;
      for(int c0=0;c0<64;c0++){
        int c=(c0+lane)&63;
        s+=hrec[(r*8+n)*64+c]*attn_s[r*64+c];
      }
      s*=0.125f;
      float mx=s;
      mx=fmaxf(mx,__shfl_xor(mx,1,8));
      mx=fmaxf(mx,__shfl_xor(mx,2,8));
      mx=fmaxf(mx,__shfl_xor(mx,4,8));
      float e=__expf(s-mx);
      float sm=e;
      sm+=__shfl_xor(sm,1,8); sm+=__shfl_xor(sm,2,8); sm+=__shfl_xor(sm,4,8);
      qbuf[tid]=e/sm;
    }
    __syncthreads();   // B4
    { // hbar -> attn_s (qk dead)
      #pragma unroll
      for(int ri=0;ri<4;ri++){
        int r=rb+ri; float sa=0.f;
        #pragma unroll
        for(int n=0;n<8;n++) sa+=qbuf[r*8+n]*hrec[(r*8+n)*64+u];
        attn_s[r*64+u]=sa;
      }
    }
    __syncthreads();   // B5
    { // h_tsa = relu(hbar@VF.T + h_ts@FwB.T + Fb') -> h9 slot0 split
      float a[4]={0,0,0,0};
      for(int k=0;k<64;k+=4){
        #pragma unroll
        for(int kk=0;kk<4;kk++){
          float wv1=P.VFt[(k+kk)*64+u], wv2=P.FBt[(k+kk)*64+u];
          #pragma unroll
          for(int ri=0;ri<4;ri++)
            a[ri]+=attn_s[(rb+ri)*64+k+kk]*wv1 + h_ts[(rb+ri)*64+k+kk]*wv2;
        }
      }
      float b=P.Fbp[u];
      #pragma unroll
      for(int ri=0;ri<4;ri++){
        float val=fmaxf(a[ri]+b,0.f);
        int row=rb+ri;
        unsigned short hb=bf_hi(val);
        *(unsigned short*)(h9+h9_off(0,0,row,u))=hb;
        *(unsigned short*)(h9+h9_off(0,1,row,u))=bf_hi(val-bf_f(hb));
      }
    }
    __syncthreads();   // B6

    if(t<T_SZ-1){
      { // f_ts -> attn_s (hbar dead)
        float a[4]={0,0,0,0};
        for(int k=0;k<64;k+=4){
          #pragma unroll
          for(int kk=0;kk<4;kk++){
            float w=P.F1Bt[(k+kk)*64+u];
            #pragma unroll
            for(int ri=0;ri<4;ri++) a[ri]+=h_ts[(rb+ri)*64+k+kk]*w;
          }
        }
        float b=P.f1b[u];
        #pragma unroll
        for(int ri=0;ri<4;ri++) attn_s[(rb+ri)*64+u]=a[ri]+b;
      }
      __syncthreads(); // B7
      // fusion: reads hrec (copy) + f_ts, writes h9 slots 1..8 — no intra-phase race
      for(int n=0;n<8;n++){
        float a0=0,a1=0,a2=0,a3=0;
        for(int k=0;k<64;k+=4){
          #pragma unroll
          for(int kk=0;kk<4;kk++){
            float w=P.F1At[(k+kk)*64+u];
            a0+=hrec[((rb+0)*8+n)*64+k+kk]*w; a1+=hrec[((rb+1)*8+n)*64+k+kk]*w;
            a2+=hrec[((rb+2)*8+n)*64+k+kk]*w; a3+=hrec[((rb+3)*8+n)*64+k+kk]*w;
          }
        }
        float av[4]={a0,a1,a2,a3};
        #pragma unroll
        for(int ri=0;ri<4;ri++){
          int row=rb+ri;
          float val=fmaxf(av[ri]+attn_s[row*64+u],0.f);
          unsigned short hb=bf_hi(val);
          *(unsigned short*)(h9+h9_off(n+1,0,row,u))=hb;
          *(unsigned short*)(h9+h9_off(n+1,1,row,u))=bf_hi(val-bf_f(hb));
        }
      }
      __syncthreads(); // B8
    }
  }

  // ---- final MLP from h_tsa (slot0 split) ----
  {
    int r=tid>>4, ii=tid&15;
    int i0=ii, i1=ii+16;
    float h0=P.m1b[i0], h1=P.m1b[i1];
    for(int k=0;k<64;k++){
      float x=h9_read(h9,0,r,k);
      h0+=x*P.m1w[(size_t)i0*64+k];
      h1+=x*P.m1w[(size_t)i1*64+k];
    }
    attn_s[r*32+i0]=fmaxf(h0,0.f);
    attn_s[r*32+i1]=fmaxf(h1,0.f);
  }
  __syncthreads();
  if(tid<R_WG){
    float s=P.m2b[0];
    for(int i=0;i<32;i++) s+=attn_s[tid*32+i]*P.m2w[i];
    P.out[r0+tid]=s;
  }
}

// ---- prep: MFMA weight chunks, split-bf16, frag-ready layout ----
// chunk (lt, cc=ks*2+s): [w*4+nt][lane][8 bf16]; K-layout: k<64 Whh, 64..79 Wih*emb, 80..95 zero
__global__ void prep_wm(const float* eW, const float* eU, const float* e2W, const float* e2U,
                        const float* emb_w, unsigned short* dst){
  int id=blockIdx.x*256+threadIdx.x;
  if(id>=108*3*16*64) return;
  int lane=id&63;
  int q=id>>6;
  int wnt=q&15;
  int q2=q>>4;
  int ks=q2%3;
  int lt=q2/3;
  int LL=lt/12, t=lt%12;
  int G=(wnt>>2)*64 + (wnt&3)*16 + (lane&15);
  int u=G>>2, gtt=G&3, jg=gtt*64+u;
  #pragma unroll
  for(int j=0;j<8;j++){
    int k=ks*32+(lane>>4)*8+j;
    float v=0.f;
    if(k<64){
      v=(LL==0)? eU[((size_t)t*256+jg)*64+k]
               : e2U[(((size_t)(LL-1)*12+t)*256+jg)*64+k];
    } else if(k<80){
      int kx=k-64;
      const float* Wi=(LL==0)? eW+((size_t)t*256+jg)*32
                             : e2W+(((size_t)(LL-1)*12+t)*256+jg)*32;
      float s=0.f;
      for(int i=0;i<32;i++) s+=Wi[i]*emb_w[i*16+kx];
      v=s;
    }
    unsigned short hi=bf_hi(v), lo=bf_hi(v-bf_f(hi));
    size_t base=((size_t)lt*6+ks*2)*8192 + ((size_t)wnt*64+lane)*8 + j;
    dst[base]=hi;
    dst[base+8192]=lo;
  }
}

__global__ void prep_b_kernel(const float* bih, const float* bhh, const float* Wih,
                              const float* emb_b, float* dst, int L){
  int idx=blockIdx.x*256+threadIdx.x;
  if(idx>=L*64) return;
  int l=idx/64, u=idx&63;
  #pragma unroll
  for(int g=0;g<4;g++){
    int j=g*64+u;
    float s=bih[l*256+j]+bhh[l*256+j];
    for(int i=0;i<32;i++) s+=Wih[((size_t)l*256+j)*32+i]*emb_b[i];
    dst[l*256+u*4+g]=s;
  }
}

__global__ void prep_att2(const float* Qw, const float* Vw, const float* Vb,
                          const float* Fw, const float* Fb, const float* f1w,
                          float* Qt, float* VFt, float* FBt, float* F1At, float* F1Bt, float* Fbp){
  int id=blockIdx.x*256+threadIdx.x;
  if(id>=4096) return;
  int k=id>>6, u=id&63;
  Qt[k*64+u]  = Qw[u*64+k];
  FBt[k*64+u] = Fw[u*128+64+k];
  F1At[k*64+u]= f1w[u*128+k];
  F1Bt[k*64+u]= f1w[u*128+64+k];
  float s=0.f;
  for(int m=0;m<64;m++) s+=Fw[u*128+m]*Vw[m*64+k];
  VFt[k*64+u]=s;
  if(k==0){
    float sb=Fb[u];
    for(int m=0;m<64;m++) sb+=Fw[u*128+m]*Vb[m];
    Fbp[u]=sb;
  }
}

extern "C" void kernel_launch(void* const* d_in, const int* in_sizes, int n_in,
                              void* d_out, int out_size, void* d_ws, size_t ws_size,
                              hipStream_t stream){
  const float* ts      =(const float*)d_in[0];
  const float* gts     =(const float*)d_in[1];
  const float* emb_w   =(const float*)d_in[2];
  const float* emb_b   =(const float*)d_in[3];
  const float* attQ_w  =(const float*)d_in[4];
  const float* attQ_b  =(const float*)d_in[5];
  const float* attK_w  =(const float*)d_in[6];
  // d_in[7] attK_b: softmax-invariant, unused
  const float* attV_w  =(const float*)d_in[8];
  const float* attV_b  =(const float*)d_in[9];
  const float* attF_w  =(const float*)d_in[10];
  const float* attF_b  =(const float*)d_in[11];
  const float* fuse1_w =(const float*)d_in[12];
  const float* fuse1_b =(const float*)d_in[13];
  const float* enc_Wih =(const float*)d_in[14];
  const float* enc_Whh =(const float*)d_in[15];
  const float* enc_bih =(const float*)d_in[16];
  const float* enc_bhh =(const float*)d_in[17];
  const float* enc2_Wih=(const float*)d_in[18];
  const float* enc2_Whh=(const float*)d_in[19];
  const float* enc2_bih=(const float*)d_in[20];
  const float* enc2_bhh=(const float*)d_in[21];
  const float* mlp1_w  =(const float*)d_in[22];
  const float* mlp1_b  =(const float*)d_in[23];
  const float* mlp2_w  =(const float*)d_in[24];
  const float* mlp2_b  =(const float*)d_in[25];

  char* ws=(char*)d_ws;
  size_t off=0;
  unsigned short* Wm=(unsigned short*)(ws+off); off+=(size_t)108*6*8192*2;
  float* b4ts=(float*)(ws+off); off+=12*256*4;
  float* b4nd=(float*)(ws+off); off+=96*256*4;
  float* Qt  =(float*)(ws+off); off+=4096*4;
  float* VFt =(float*)(ws+off); off+=4096*4;
  float* FBt =(float*)(ws+off); off+=4096*4;
  float* F1At=(float*)(ws+off); off+=4096*4;
  float* F1Bt=(float*)(ws+off); off+=4096*4;
  float* Fbp =(float*)(ws+off); off+=64*4;
  float* cg  =(float*)(ws+off); off+=(size_t)9*8192*64*4;

  prep_wm<<<(108*3*16*64+255)/256,256,0,stream>>>(enc_Wih,enc_Whh,enc2_Wih,enc2_Whh,emb_w,Wm);
  prep_b_kernel<<<(12*64+255)/256,256,0,stream>>>(enc_bih,enc_bhh,enc_Wih,emb_b,b4ts,12);
  prep_b_kernel<<<(96*64+255)/256,256,0,stream>>>(enc2_bih,enc2_bhh,enc2_Wih,emb_b,b4nd,96);
  prep_att2<<<16,256,0,stream>>>(attQ_w,attV_w,attV_b,attF_w,attF_b,fuse1_w,
                                 Qt,VFt,FBt,F1At,F1Bt,Fbp);

  Ptrs P;
  P.ts=ts; P.gts=gts; P.Wm=Wm; P.b4ts=b4ts; P.b4nd=b4nd;
  P.Qt=Qt; P.Qb=attQ_b; P.Kw=attK_w;
  P.VFt=VFt; P.FBt=FBt; P.Fbp=Fbp;
  P.F1At=F1At; P.F1Bt=F1Bt; P.f1b=fuse1_b;
  P.m1w=mlp1_w; P.m1b=mlp1_b; P.m2w=mlp2_w; P.m2b=mlp2_b;
  P.cg=cg; P.out=(float*)d_out;

  fused_kernel<<<NWG,NTHR,0,stream>>>(P);
}

// Round 9
// 671.352 us; speedup vs baseline: 4.6681x; 3.8600x over previous
//
#include <hip/hip_runtime.h>

#define T_SZ 12
#define R_WG 16
#define NTHR 256
#define NWG  512   // 8192/16

typedef float vf4 __attribute__((ext_vector_type(4)));
typedef int   vi4 __attribute__((ext_vector_type(4)));
typedef __bf16 vbf8 __attribute__((ext_vector_type(8)));
typedef const __attribute__((address_space(1))) void* gas1_t;
typedef __attribute__((address_space(3))) void* las3_t;

__device__ __forceinline__ void gload16(const void* g, void* l){
  __builtin_amdgcn_global_load_lds((gas1_t)g,(las3_t)l,16,0,0);
}
__device__ __forceinline__ float sigm(float x){ return 1.f/(1.f+__expf(-x)); }
__device__ __forceinline__ float tanh_f(float x){
  float e=__expf(-2.f*fabsf(x)); float t=(1.f-e)/(1.f+e); return x<0.f?-t:t;
}
__device__ __forceinline__ unsigned short bf_hi(float f){
  unsigned int b=__float_as_uint(f);
  return (unsigned short)((b + 0x7fffu + ((b>>16)&1u))>>16);
}
__device__ __forceinline__ float bf_f(unsigned short h){
  return __uint_as_float(((unsigned int)h)<<16);
}
// Builtin MFMA (hazard-modeled by compiler; inline-asm v_mfma got no hazard nops).
__device__ __forceinline__ vf4 mfma16(vi4 a, vi4 b, vf4 c){
  return __builtin_amdgcn_mfma_f32_16x16x32_bf16(
      __builtin_bit_cast(vbf8,a), __builtin_bit_cast(vbf8,b), c, 0, 0, 0);
}
#define WAITV(N) do{ asm volatile("s_waitcnt vmcnt(" #N ")" ::: "memory"); __builtin_amdgcn_sched_barrier(0); }while(0)
#define BAR()    do{ asm volatile("s_waitcnt lgkmcnt(0)" ::: "memory"); __builtin_amdgcn_s_barrier(); __builtin_amdgcn_sched_barrier(0); }while(0)
// Drain this wave's LDS reads before re-issuing a DMA into the buffer they read.
// (gload_lds write lands at data-return; without this, a contended ds_read can be
// serviced AFTER the DMA write -> MFMA consumes next-chunk bytes.)
#define LWAIT()  asm volatile("s_waitcnt lgkmcnt(0)" ::: "memory")

// stage this wave's 4KB quarter of a 16KB chunk (4 gload16/thread, self-contained)
__device__ __forceinline__ void issue4(const char* gsrc, char* lbuf, int wv, int ln){
  #pragma unroll
  for(int j=0;j<4;j++){
    int idx=((wv<<2)+j)<<6;
    gload16(gsrc+(size_t)(idx+ln)*16, lbuf+(size_t)idx*16);
  }
}

// split-bf16 h slots: slot*4096 + [split(2048)] + (row*8 + ((k>>3)^(row&7)))*16 + (k&7)*2
__device__ __forceinline__ void a_read(const char* h9,int slot,int ks,int arow,int kb,vi4& Ah,vi4& Al){
  int blk=((ks<<2)+kb)^(arow&7);
  const char* p=h9+slot*4096+(arow*8+blk)*16;
  Ah=*(const vi4*)p; Al=*(const vi4*)(p+2048);
}
__device__ __forceinline__ void h9_w1(char* h9,int slot,int row,int k,float v){
  int off=slot*4096+(row*8+((k>>3)^(row&7)))*16+(k&7)*2;
  unsigned short hi=bf_hi(v);
  *(unsigned short*)(h9+off)=hi;
  *(unsigned short*)(h9+off+2048)=bf_hi(v-bf_f(hi));
}
__device__ __forceinline__ void h9_w4(char* h9,int slot,int row,int k0,float v0,float v1,float v2,float v3){
  int off=slot*4096+(row*8+((k0>>3)^(row&7)))*16+(k0&7)*2;
  unsigned short h0=bf_hi(v0),h1=bf_hi(v1),h2=bf_hi(v2),h3=bf_hi(v3);
  uint2 hv; hv.x=(unsigned)h0|((unsigned)h1<<16); hv.y=(unsigned)h2|((unsigned)h3<<16);
  *(uint2*)(h9+off)=hv;
  uint2 lv;
  lv.x=(unsigned)bf_hi(v0-bf_f(h0))|((unsigned)bf_hi(v1-bf_f(h1))<<16);
  lv.y=(unsigned)bf_hi(v2-bf_f(h2))|((unsigned)bf_hi(v3-bf_f(h3))<<16);
  *(uint2*)(h9+off+2048)=lv;
}
__device__ __forceinline__ float h9_rd(const char* h9,int slot,int row,int k){
  int off=slot*4096+(row*8+((k>>3)^(row&7)))*16+(k&7)*2;
  return bf_f(*(const unsigned short*)(h9+off))+bf_f(*(const unsigned short*)(h9+off+2048));
}

// LSTM chunk computes: blocks (wv*4+nt), N=256
__device__ __forceinline__ void lstm_hi(vf4&a0,vf4&a1,vf4&a2,vf4&a3,vi4 Ah,vi4 Al,const char* buf,int wv,int ln){
  vi4 B;
  B=*(const vi4*)(buf+(size_t)(((wv<<2)+0)*64+ln)*16); a0=mfma16(Ah,B,a0); a0=mfma16(Al,B,a0);
  B=*(const vi4*)(buf+(size_t)(((wv<<2)+1)*64+ln)*16); a1=mfma16(Ah,B,a1); a1=mfma16(Al,B,a1);
  B=*(const vi4*)(buf+(size_t)(((wv<<2)+2)*64+ln)*16); a2=mfma16(Ah,B,a2); a2=mfma16(Al,B,a2);
  B=*(const vi4*)(buf+(size_t)(((wv<<2)+3)*64+ln)*16); a3=mfma16(Ah,B,a3); a3=mfma16(Al,B,a3);
}
__device__ __forceinline__ void lstm_lo(vf4&a0,vf4&a1,vf4&a2,vf4&a3,vi4 Ah,const char* buf,int wv,int ln){
  vi4 B;
  B=*(const vi4*)(buf+(size_t)(((wv<<2)+0)*64+ln)*16); a0=mfma16(Ah,B,a0);
  B=*(const vi4*)(buf+(size_t)(((wv<<2)+1)*64+ln)*16); a1=mfma16(Ah,B,a1);
  B=*(const vi4*)(buf+(size_t)(((wv<<2)+2)*64+ln)*16); a2=mfma16(Ah,B,a2);
  B=*(const vi4*)(buf+(size_t)(((wv<<2)+3)*64+ln)*16); a3=mfma16(Ah,B,a3);
}
// attention GEMM: K=64, N=64, chunk blocks [colblk=wv][ks][split]
__device__ __forceinline__ void agemm(vf4& acc,const char* h9,int slot,const char* buf,int wv,int ln){
  int arow=ln&15, kb=ln>>4;
  vi4 Ah,Al,B;
  a_read(h9,slot,0,arow,kb,Ah,Al);
  B=*(const vi4*)(buf+(size_t)(((wv<<2)+0)*64+ln)*16); acc=mfma16(Ah,B,acc); acc=mfma16(Al,B,acc);
  B=*(const vi4*)(buf+(size_t)(((wv<<2)+1)*64+ln)*16); acc=mfma16(Ah,B,acc);
  a_read(h9,slot,1,arow,kb,Ah,Al);
  B=*(const vi4*)(buf+(size_t)(((wv<<2)+2)*64+ln)*16); acc=mfma16(Ah,B,acc); acc=mfma16(Al,B,acc);
  B=*(const vi4*)(buf+(size_t)(((wv<<2)+3)*64+ln)*16); acc=mfma16(Ah,B,acc);
}

struct Ptrs {
  const float* ts; const float* gts;
  const unsigned short* Wm; const unsigned short* Wa;
  const float* Qb; const float* Fbp; const float* f1b;
  const float* m1w; const float* m1b; const float* m2w; const float* m2b;
  float* cg; float* out;
};

__global__ __launch_bounds__(NTHR,2) void fused_kernel(Ptrs P){
  __shared__ __align__(16) char  h9[45056];     // 11 slots x 4KB (0=h_tsa,1..8=nodes,9=h_ts,10=q/hbar)
  __shared__ __align__(16) char  ring[32768];   // 2 x 16KB chunk ring
  __shared__ __align__(16) float attn_s[1024];  // qk fp32 / p

  const int tid=threadIdx.x;
  const int r0=blockIdx.x*R_WG;
  const int wv=tid>>6, ln=tid&63;
  const int arow=ln&15, kb=ln>>4, qq=ln&3;
  const int rowN=(kb<<2)|qq;                      // nonlin row ownership
  const int ub = wv*16 + ((ln>>2)&3)*4;           // nonlin u-base (4 consecutive u)
  const int colw = wv*16 + arow;                  // attn C-layout col
  const int crow0 = kb<<2;                        // C-layout row base
  char* buf0=ring; char* buf1=ring+16384;
  const char* Wmb=(const char*)P.Wm;
  const char* Wab=(const char*)P.Wa;
  #define WCH(l_,c_) (Wmb + (((size_t)(l_)*12+(size_t)t)*6+(size_t)(c_))*16384)

  // Bias loads issued and DRAINED before the counted-vmcnt ledger starts, so the
  // scheduler cannot interleave them with the staged chunk loads.
  float bQ =P.Qb [colw];
  float bF =P.Fbp[colw];
  float bf1v=P.f1b[colw];
  asm volatile("s_waitcnt vmcnt(0)" ::: "memory");

  for(int i=tid;i<45056/16;i+=NTHR) ((vi4*)h9)[i]=(vi4){0,0,0,0};

  vf4 xa_c={0,0,0,0},xb_c={0,0,0,0},xa_n={0,0,0,0},xb_n={0,0,0,0};
  vf4 cvec_c={0,0,0,0},cvec_n={0,0,0,0};

  // prologue: issue l0c0(4), l0c1(4), x(2), c(1)  -> first W0 = vmcnt(7)
  issue4(Wmb+0*16384, buf0, wv, ln);
  issue4(Wmb+1*16384, buf1, wv, ln);
  if(kb<2){
    const float* xs=P.ts+(size_t)(r0+arow)*192 + kb*8;
    xa_c=*(const vf4*)xs; xb_c=*(const vf4*)(xs+4);
  }
  cvec_c=*(const vf4*)(P.cg + ((size_t)0*8192 + r0+rowN)*64 + ub);
  BAR();   // zeros visible; vm stays outstanding

  for(int t=0;t<T_SZ;t++){
    // ================= 9 LSTMs (chunks c0..c5 each, ring, counted vmcnt) =================
    #pragma unroll 1
    for(int l=0;l<9;l++){
      const int slotA=(l==0)?0:l;
      vf4 a0={0,0,0,0},a1={0,0,0,0},a2={0,0,0,0},a3={0,0,0,0};
      vi4 Ah,Al;
      // c0: ks0 hi
      if(l==0) WAITV(7); else WAITV(5);
      a_read(h9,slotA,0,arow,kb,Ah,Al);
      lstm_hi(a0,a1,a2,a3,Ah,Al,buf0,wv,ln);
      LWAIT();
      issue4(WCH(l,2),buf0,wv,ln);
      if(l<8){
        const float* xs=P.gts+(size_t)(r0+arow)*1536 + (size_t)l*192 + (size_t)t*16 + kb*8;
        if(kb<2){ xa_n=*(const vf4*)xs; xb_n=*(const vf4*)(xs+4); }
        cvec_n=*(const vf4*)(P.cg + ((size_t)(l+1)*8192 + r0+rowN)*64 + ub);
      }
      // c1: ks0 lo
      if(l<8) WAITV(7); else WAITV(4);
      lstm_lo(a0,a1,a2,a3,Ah,buf1,wv,ln);
      LWAIT();
      issue4(WCH(l,3),buf1,wv,ln);
      // c2: ks1 hi
      if(l<8) WAITV(7); else WAITV(4);
      a_read(h9,slotA,1,arow,kb,Ah,Al);
      lstm_hi(a0,a1,a2,a3,Ah,Al,buf0,wv,ln);
      LWAIT();
      issue4(WCH(l,4),buf0,wv,ln);
      // c3: ks1 lo
      WAITV(4);
      lstm_lo(a0,a1,a2,a3,Ah,buf1,wv,ln);
      LWAIT();
      issue4(WCH(l,5),buf1,wv,ln);
      // c4: ks2 hi (x | bias-1 | 0)
      WAITV(4);
      {
        vi4 xh,xl;
        if(kb<2){
          float xf[8]={xa_c[0],xa_c[1],xa_c[2],xa_c[3],xb_c[0],xb_c[1],xb_c[2],xb_c[3]};
          unsigned short hh[8],llo[8];
          #pragma unroll
          for(int j=0;j<8;j++){ hh[j]=bf_hi(xf[j]); llo[j]=bf_hi(xf[j]-bf_f(hh[j])); }
          xh=(vi4){(int)((unsigned)hh[0]|((unsigned)hh[1]<<16)),(int)((unsigned)hh[2]|((unsigned)hh[3]<<16)),
                   (int)((unsigned)hh[4]|((unsigned)hh[5]<<16)),(int)((unsigned)hh[6]|((unsigned)hh[7]<<16))};
          xl=(vi4){(int)((unsigned)llo[0]|((unsigned)llo[1]<<16)),(int)((unsigned)llo[2]|((unsigned)llo[3]<<16)),
                   (int)((unsigned)llo[4]|((unsigned)llo[5]<<16)),(int)((unsigned)llo[6]|((unsigned)llo[7]<<16))};
        } else if(kb==2){ xh=(vi4){0x3F80,0,0,0}; xl=(vi4){0,0,0,0}; }
        else            { xh=(vi4){0,0,0,0};     xl=(vi4){0,0,0,0}; }
        Ah=xh; Al=xl;
      }
      lstm_hi(a0,a1,a2,a3,Ah,Al,buf0,wv,ln);
      LWAIT();
      if(l<8) issue4(WCH(l+1,0),buf0,wv,ln);
      else    issue4(Wab+0*16384,buf0,wv,ln);     // Qwc
      // c5: ks2 lo
      WAITV(4);
      lstm_lo(a0,a1,a2,a3,Ah,buf1,wv,ln);
      BAR();   // all A-reads of slot l complete before nonlin writes it (drains lgkm)
      // nonlin: quad-transpose -> each lane owns (rowN, u=ub..ub+3)
      {
        float hh4[4],cc4[4];
        auto donl=[&](vf4 av,int nt){
          float v0=av[0],v1=av[1],v2=av[2],v3=av[3];
          auto sel=[&](int e)->float{ return e==0?v0:(e==1?v1:(e==2?v2:v3)); };
          float own=sel(qq);
          float r1=__shfl_xor(sel(qq^1),1);
          float r2=__shfl_xor(sel(qq^2),2);
          float r3=__shfl_xor(sel(qq^3),3);
          float gi=(qq==0)?own:((qq==1)?r1:((qq==2)?r2:r3));
          float gf=(qq==1)?own:((qq==0)?r1:((qq==3)?r2:r3));
          float gg=(qq==2)?own:((qq==3)?r1:((qq==0)?r2:r3));
          float go=(qq==3)?own:((qq==2)?r1:((qq==1)?r2:r3));
          float cold=(t==0)?0.f:cvec_c[nt];
          float iv=sigm(gi),fv=sigm(gf),gv=tanh_f(gg),ov=sigm(go);
          float c2=fv*cold+iv*gv;
          cc4[nt]=c2; hh4[nt]=ov*tanh_f(c2);
        };
        donl(a0,0); donl(a1,1); donl(a2,2); donl(a3,3);
        *(vf4*)(P.cg + ((size_t)l*8192 + r0+rowN)*64 + ub) = (vf4){cc4[0],cc4[1],cc4[2],cc4[3]};
        h9_w4(h9,(l==0)?9:l,rowN,ub,hh4[0],hh4[1],hh4[2],hh4[3]);
      }
      if(l<8) issue4(WCH(l+1,1),buf1,wv,ln);
      else    issue4(Wab+1*16384,buf1,wv,ln);     // Kwc
      xa_c=xa_n; xb_c=xb_n; cvec_c=cvec_n;
    }

    // ================= attention / fusion (all MFMA, same ring) =================
    vf4 acA, facc;
    // phQ: q = h_ts@Qw.T + Qb  -> slot10
    WAITV(5);
    acA=(vf4){bQ,bQ,bQ,bQ};
    agemm(acA,h9,9,buf0,wv,ln);
    LWAIT();
    issue4(Wab+2*16384,buf0,wv,ln);               // VFc
    #pragma unroll
    for(int rg=0;rg<4;rg++) h9_w1(h9,10,crow0+rg,colw,acA[rg]);
    BAR();
    // phK: qk = q@(0.125*Kw) -> attn_s fp32
    WAITV(4);
    acA=(vf4){0,0,0,0};
    agemm(acA,h9,10,buf1,wv,ln);
    LWAIT();
    issue4(Wab+3*16384,buf1,wv,ln);               // FBc
    #pragma unroll
    for(int rg=0;rg<4;rg++) attn_s[(crow0+rg)*64+colw]=acA[rg];
    BAR();
    // phS: scores + softmax. Two-phase p store (compute in regs, BAR, store, BAR).
    float pval=0.f;
    if(tid<128){
      int rr=tid>>3;
      int nn=tid&7;
      const char* hp=h9+(nn+1)*4096;
      float s=0.f;
      #pragma unroll
      for(int kbl=0;kbl<8;kbl++){
        int blk=kbl^(rr&7);
        const char* pp=hp+(rr*8+blk)*16;
        vi4 hv=*(const vi4*)pp;
        vi4 lv=*(const vi4*)(pp+2048);
        const float* qkp=attn_s+rr*64+kbl*8;
        #pragma unroll
        for(int e=0;e<4;e++){
          unsigned hw=((const unsigned*)&hv)[e], lw=((const unsigned*)&lv)[e];
          float w0=__uint_as_float(hw<<16)+__uint_as_float(lw<<16);
          float w1=__uint_as_float(hw&0xffff0000u)+__uint_as_float(lw&0xffff0000u);
          s+=w0*qkp[e*2]+w1*qkp[e*2+1];
        }
      }
      float mx=s;
      mx=fmaxf(mx,__shfl_xor(mx,1));
      mx=fmaxf(mx,__shfl_xor(mx,2));
      mx=fmaxf(mx,__shfl_xor(mx,4));
      float e=__expf(s-mx);
      float sm=e;
      sm+=__shfl_xor(sm,1); sm+=__shfl_xor(sm,2); sm+=__shfl_xor(sm,4);
      pval=e/sm;
    }
    BAR();
    if(tid<128) attn_s[tid]=pval;    // p[row][n]
    BAR();
    // phH: hbar = sum_n p_n h_n -> slot10 (q dead)
    {
      int uu=tid&63, rbh=(tid>>6)*4;
      #pragma unroll
      for(int ri=0;ri<4;ri++){
        int row=rbh+ri;
        float sa=0.f;
        #pragma unroll
        for(int n=0;n<8;n++) sa+=attn_s[row*8+n]*h9_rd(h9,n+1,row,uu);
        h9_w1(h9,10,row,uu,sa);
      }
    }
    BAR();
    // phC+phB: h_tsa = relu(VF*hbar + FB*h_ts + Fbp) -> slot0
    WAITV(4);
    acA=(vf4){bF,bF,bF,bF};
    agemm(acA,h9,10,buf0,wv,ln);
    LWAIT();
    issue4(Wab+4*16384,buf0,wv,ln);               // F1Bc
    WAITV(4);
    agemm(acA,h9,9,buf1,wv,ln);
    LWAIT();
    issue4(Wab+5*16384,buf1,wv,ln);               // F1Ac
    #pragma unroll
    for(int rg=0;rg<4;rg++) h9_w1(h9,0,crow0+rg,colw,fmaxf(acA[rg],0.f));
    if(t==T_SZ-1) break;
    // phF: f_ts = h_ts@F1B.T + f1b  (kept in regs; consumed at same (row,col) by fusion)
    WAITV(4);
    facc=(vf4){bf1v,bf1v,bf1v,bf1v};
    agemm(facc,h9,9,buf0,wv,ln);
    LWAIT();
    issue4(Wmb + (((size_t)0*12+(size_t)(t+1))*6+0)*16384, buf0,wv,ln);   // l0c0(t+1)
    // phX: fusion h_n = relu(h_n@F1A.T + f_ts) for n=1..8
    WAITV(4);
    {
      vf4 g1=facc,g2=facc,g3=facc,g4=facc,g5=facc,g6=facc,g7=facc,g8=facc;
      agemm(g1,h9,1,buf1,wv,ln); agemm(g2,h9,2,buf1,wv,ln);
      agemm(g3,h9,3,buf1,wv,ln); agemm(g4,h9,4,buf1,wv,ln);
      agemm(g5,h9,5,buf1,wv,ln); agemm(g6,h9,6,buf1,wv,ln);
      agemm(g7,h9,7,buf1,wv,ln); agemm(g8,h9,8,buf1,wv,ln);
      BAR();   // all slot reads done before overwrite (drains lgkm)
      #pragma unroll
      for(int rg=0;rg<4;rg++){
        h9_w1(h9,1,crow0+rg,colw,fmaxf(g1[rg],0.f));
        h9_w1(h9,2,crow0+rg,colw,fmaxf(g2[rg],0.f));
        h9_w1(h9,3,crow0+rg,colw,fmaxf(g3[rg],0.f));
        h9_w1(h9,4,crow0+rg,colw,fmaxf(g4[rg],0.f));
        h9_w1(h9,5,crow0+rg,colw,fmaxf(g5[rg],0.f));
        h9_w1(h9,6,crow0+rg,colw,fmaxf(g6[rg],0.f));
        h9_w1(h9,7,crow0+rg,colw,fmaxf(g7[rg],0.f));
        h9_w1(h9,8,crow0+rg,colw,fmaxf(g8[rg],0.f));
      }
    }
    issue4(Wmb + (((size_t)0*12+(size_t)(t+1))*6+1)*16384, buf1,wv,ln);   // l0c1(t+1)
    if(kb<2){
      const float* xs=P.ts+(size_t)(r0+arow)*192 + (size_t)(t+1)*16 + kb*8;
      xa_n=*(const vf4*)xs; xb_n=*(const vf4*)(xs+4);
    }
    cvec_n=*(const vf4*)(P.cg + ((size_t)0*8192 + r0+rowN)*64 + ub);
    BAR();   // new slots visible for next t
    xa_c=xa_n; xb_c=xb_n; cvec_c=cvec_n;
  }

  // ================= final MLP from slot0 (h_tsa) =================
  WAITV(0);
  BAR();
  {
    int rr=tid>>4, ii=tid&15;
    #pragma unroll
    for(int jj=0;jj<2;jj++){
      int i=ii+jj*16;
      float h=P.m1b[i];
      for(int k=0;k<64;k++) h+=h9_rd(h9,0,rr,k)*P.m1w[(size_t)i*64+k];
      attn_s[rr*32+i]=fmaxf(h,0.f);
    }
  }
  BAR();
  if(tid<R_WG){
    float s=P.m2b[0];
    for(int i=0;i<32;i++) s+=attn_s[tid*32+i]*P.m2w[i];
    P.out[r0+tid]=s;
  }
  #undef WCH
}

// ---- prep: LSTM weight chunks, split-bf16, frag layout; bias folded at k=80 ----
__global__ void prep_wm(const float* eW, const float* eU, const float* e2W, const float* e2U,
                        const float* emb_w, const float* eb_ih, const float* eb_hh,
                        const float* e2b_ih, const float* e2b_hh, const float* emb_b,
                        unsigned short* dst){
  int id=blockIdx.x*256+threadIdx.x;
  if(id>=108*3*16*64) return;
  int lane=id&63;
  int q=id>>6;
  int wnt=q&15;
  int q2=q>>4;
  int ks=q2%3;
  int lt=q2/3;
  int LL=lt/12, t=lt%12;
  int c15=lane&15;
  int u=(wnt>>2)*16+(c15>>2)*4+(wnt&3);
  int gt=c15&3;
  int jg=gt*64+u;
  const float* Whh=(LL==0)? eU+((size_t)t*256+jg)*64 : e2U+(((size_t)(LL-1)*12+t)*256+jg)*64;
  const float* Wih=(LL==0)? eW+((size_t)t*256+jg)*32 : e2W+(((size_t)(LL-1)*12+t)*256+jg)*32;
  float bsum;
  {
    float bi=(LL==0)? eb_ih[t*256+jg] : e2b_ih[((LL-1)*12+t)*256+jg];
    float bh=(LL==0)? eb_hh[t*256+jg] : e2b_hh[((LL-1)*12+t)*256+jg];
    float s=bi+bh;
    for(int i=0;i<32;i++) s+=Wih[i]*emb_b[i];
    bsum=s;
  }
  #pragma unroll
  for(int j=0;j<8;j++){
    int k=ks*32+(lane>>4)*8+j;
    float v;
    if(k<64) v=Whh[k];
    else if(k<80){
      int kx=k-64; float s=0.f;
      for(int i=0;i<32;i++) s+=Wih[i]*emb_w[i*16+kx];
      v=s;
    } else if(k==80) v=bsum;
    else v=0.f;
    unsigned short hi=bf_hi(v), lo=bf_hi(v-bf_f(hi));
    size_t base=((size_t)lt*6+ks*2)*8192 + ((size_t)wnt*64+lane)*8 + j;
    dst[base]=hi;
    dst[base+8192]=lo;
  }
}

// ---- prep: 6 attention/fusion chunks [colblk][ks][split][lane][8], + Fbp ----
__global__ void prep_attw(const float* Qw, const float* Kw, const float* Vw, const float* Vb,
                          const float* Fw, const float* Fb, const float* f1w,
                          unsigned short* dst, float* Fbp){
  int id=blockIdx.x*256+threadIdx.x;
  if(id<6144){
    int cidx=id>>10;
    int rem=id&1023;
    int block=rem>>6;
    int lane=rem&63;
    int ks=(block>>1)&1, s=block&1;
    int col=(block>>2)*16+(lane&15);
    #pragma unroll
    for(int j=0;j<8;j++){
      int k=ks*32+(lane>>4)*8+j;
      float v;
      if(cidx==0) v=Qw[col*64+k];
      else if(cidx==1) v=Kw[k*64+col]*0.125f;
      else if(cidx==2){ float sv=0.f; for(int m=0;m<64;m++) sv+=Fw[col*128+m]*Vw[m*64+k]; v=sv; }
      else if(cidx==3) v=Fw[col*128+64+k];
      else if(cidx==4) v=f1w[col*128+64+k];
      else             v=f1w[col*128+k];
      unsigned short hi=bf_hi(v);
      dst[(size_t)cidx*8192 + ((size_t)block*64+lane)*8 + j] = (s==0)? hi : bf_hi(v-bf_f(hi));
    }
  } else if(id<6144+64){
    int u=id-6144;
    float s=Fb[u];
    for(int m=0;m<64;m++) s+=Fw[u*128+m]*Vb[m];
    Fbp[u]=s;
  }
}

extern "C" void kernel_launch(void* const* d_in, const int* in_sizes, int n_in,
                              void* d_out, int out_size, void* d_ws, size_t ws_size,
                              hipStream_t stream){
  const float* ts      =(const float*)d_in[0];
  const float* gts     =(const float*)d_in[1];
  const float* emb_w   =(const float*)d_in[2];
  const float* emb_b   =(const float*)d_in[3];
  const float* attQ_w  =(const float*)d_in[4];
  const float* attQ_b  =(const float*)d_in[5];
  const float* attK_w  =(const float*)d_in[6];
  // d_in[7] attK_b: softmax-invariant, unused
  const float* attV_w  =(const float*)d_in[8];
  const float* attV_b  =(const float*)d_in[9];
  const float* attF_w  =(const float*)d_in[10];
  const float* attF_b  =(const float*)d_in[11];
  const float* fuse1_w =(const float*)d_in[12];
  const float* fuse1_b =(const float*)d_in[13];
  const float* enc_Wih =(const float*)d_in[14];
  const float* enc_Whh =(const float*)d_in[15];
  const float* enc_bih =(const float*)d_in[16];
  const float* enc_bhh =(const float*)d_in[17];
  const float* enc2_Wih=(const float*)d_in[18];
  const float* enc2_Whh=(const float*)d_in[19];
  const float* enc2_bih=(const float*)d_in[20];
  const float* enc2_bhh=(const float*)d_in[21];
  const float* mlp1_w  =(const float*)d_in[22];
  const float* mlp1_b  =(const float*)d_in[23];
  const float* mlp2_w  =(const float*)d_in[24];
  const float* mlp2_b  =(const float*)d_in[25];

  char* ws=(char*)d_ws;
  size_t off=0;
  unsigned short* Wm=(unsigned short*)(ws+off); off+=(size_t)108*6*8192*2;
  unsigned short* Wa=(unsigned short*)(ws+off); off+=(size_t)6*8192*2;
  float* Fbp=(float*)(ws+off); off+=64*4;
  float* cg =(float*)(ws+off); off+=(size_t)9*8192*64*4;

  prep_wm<<<(108*3*16*64+255)/256,256,0,stream>>>(enc_Wih,enc_Whh,enc2_Wih,enc2_Whh,emb_w,
                                                  enc_bih,enc_bhh,enc2_bih,enc2_bhh,emb_b,Wm);
  prep_attw<<<25,256,0,stream>>>(attQ_w,attK_w,attV_w,attV_b,attF_w,attF_b,fuse1_w,Wa,Fbp);

  Ptrs P;
  P.ts=ts; P.gts=gts; P.Wm=Wm; P.Wa=Wa;
  P.Qb=attQ_b; P.Fbp=Fbp; P.f1b=fuse1_b;
  P.m1w=mlp1_w; P.m1b=mlp1_b; P.m2w=mlp2_w; P.m2b=mlp2_b;
  P.cg=cg; P.out=(float*)d_out;

  fused_kernel<<<NWG,NTHR,0,stream>>>(P);
}

// Round 10
// 658.389 us; speedup vs baseline: 4.7600x; 1.0197x over previous
//
#include <hip/hip_runtime.h>

#define T_SZ 12
#define R_WG 16
#define NTHR 512
#define NWG  512   // 8192/16

typedef float  vf4 __attribute__((ext_vector_type(4)));
typedef float  vf2 __attribute__((ext_vector_type(2)));
typedef int    vi4 __attribute__((ext_vector_type(4)));
typedef __bf16 vbf8 __attribute__((ext_vector_type(8)));
typedef const __attribute__((address_space(1))) void* gas1_t;
typedef __attribute__((address_space(3))) void* las3_t;

__device__ __forceinline__ void gload16(const void* g, void* l){
  __builtin_amdgcn_global_load_lds((gas1_t)g,(las3_t)l,16,0,0);
}
__device__ __forceinline__ float sigm(float x){ return 1.f/(1.f+__expf(-x)); }
__device__ __forceinline__ float tanh_f(float x){
  float e=__expf(-2.f*fabsf(x)); float t=(1.f-e)/(1.f+e); return x<0.f?-t:t;
}
__device__ __forceinline__ unsigned short bf_hi(float f){
  unsigned int b=__float_as_uint(f);
  return (unsigned short)((b + 0x7fffu + ((b>>16)&1u))>>16);
}
__device__ __forceinline__ float bf_f(unsigned short h){
  return __uint_as_float(((unsigned int)h)<<16);
}
__device__ __forceinline__ vf4 mfma16(vi4 a, vi4 b, vf4 c){
  return __builtin_amdgcn_mfma_f32_16x16x32_bf16(
      __builtin_bit_cast(vbf8,a), __builtin_bit_cast(vbf8,b), c, 0, 0, 0);
}
#define WAITV(N) do{ asm volatile("s_waitcnt vmcnt(" #N ")" ::: "memory"); __builtin_amdgcn_sched_barrier(0); }while(0)
#define BAR()    do{ asm volatile("s_waitcnt lgkmcnt(0)" ::: "memory"); __builtin_amdgcn_s_barrier(); __builtin_amdgcn_sched_barrier(0); }while(0)
#define LWAIT()  asm volatile("s_waitcnt lgkmcnt(0)" ::: "memory")

// self-staged 2-block quarter of a 16KB chunk (blocks 2w, 2w+1) — 2 vm entries
__device__ __forceinline__ void issue2(const char* gsrc, char* lbuf, int w, int ln){
  #pragma unroll
  for(int j=0;j<2;j++){
    int blk=2*w+j;
    gload16(gsrc+(size_t)(blk*64+ln)*16, lbuf+(size_t)blk*64*16);
  }
}
// waves 0-3 stage 4 blocks (w*4..w*4+3) — used for attention chunks (self-read)
__device__ __forceinline__ void issue4(const char* gsrc, char* lbuf, int w, int ln){
  #pragma unroll
  for(int j=0;j<4;j++){
    int blk=w*4+j;
    gload16(gsrc+(size_t)(blk*64+ln)*16, lbuf+(size_t)blk*64*16);
  }
}

// split-bf16 h slots: slot*4096 + [split +2048] + (row*8 + ((k>>3)^(row&7)))*16 + (k&7)*2
__device__ __forceinline__ void a_read(const char* h9,int slot,int ks,int arow,int kb,vi4& Ah,vi4& Al){
  int blk=((ks<<2)+kb)^(arow&7);
  const char* p=h9+slot*4096+(arow*8+blk)*16;
  Ah=*(const vi4*)p; Al=*(const vi4*)(p+2048);
}
__device__ __forceinline__ void h9_w1(char* h9,int slot,int row,int k,float v){
  int off=slot*4096+(row*8+((k>>3)^(row&7)))*16+(k&7)*2;
  unsigned short hi=bf_hi(v);
  *(unsigned short*)(h9+off)=hi;
  *(unsigned short*)(h9+off+2048)=bf_hi(v-bf_f(hi));
}
// write pair (row, k0), (row, k0+1), k0 even (same 8-k block)
__device__ __forceinline__ void h9_w2(char* h9,int slot,int row,int k0,float v0,float v1){
  int off=slot*4096+(row*8+((k0>>3)^(row&7)))*16+(k0&7)*2;
  unsigned short h0=bf_hi(v0),h1=bf_hi(v1);
  *(unsigned*)(h9+off)=(unsigned)h0|((unsigned)h1<<16);
  *(unsigned*)(h9+off+2048)=(unsigned)bf_hi(v0-bf_f(h0))|((unsigned)bf_hi(v1-bf_f(h1))<<16);
}
__device__ __forceinline__ float h9_rd(const char* h9,int slot,int row,int k){
  int off=slot*4096+(row*8+((k>>3)^(row&7)))*16+(k&7)*2;
  return bf_f(*(const unsigned short*)(h9+off))+bf_f(*(const unsigned short*)(h9+off+2048));
}

// LSTM per-wave: 2 N-blocks (2w, 2w+1)
__device__ __forceinline__ void lstm_hi2(vf4&a0,vf4&a1,vi4 Ah,vi4 Al,const char* buf,int w,int ln){
  vi4 B;
  B=*(const vi4*)(buf+(size_t)((2*w+0)*64+ln)*16); a0=mfma16(Ah,B,a0); a0=mfma16(Al,B,a0);
  B=*(const vi4*)(buf+(size_t)((2*w+1)*64+ln)*16); a1=mfma16(Ah,B,a1); a1=mfma16(Al,B,a1);
}
__device__ __forceinline__ void lstm_lo2(vf4&a0,vf4&a1,vi4 Ah,const char* buf,int w,int ln){
  vi4 B;
  B=*(const vi4*)(buf+(size_t)((2*w+0)*64+ln)*16); a0=mfma16(Ah,B,a0);
  B=*(const vi4*)(buf+(size_t)((2*w+1)*64+ln)*16); a1=mfma16(Ah,B,a1);
}
// attention GEMM (waves 0-3): K=64,N=64; wave w reads its self-staged blocks w*4..w*4+3
__device__ __forceinline__ void agemm(vf4& acc,const char* h9,int slot,const char* buf,int w,int ln){
  int arow=ln&15, kb=ln>>4;
  vi4 Ah,Al,B;
  a_read(h9,slot,0,arow,kb,Ah,Al);
  B=*(const vi4*)(buf+(size_t)((w*4+0)*64+ln)*16); acc=mfma16(Ah,B,acc); acc=mfma16(Al,B,acc);
  B=*(const vi4*)(buf+(size_t)((w*4+1)*64+ln)*16); acc=mfma16(Ah,B,acc);
  a_read(h9,slot,1,arow,kb,Ah,Al);
  B=*(const vi4*)(buf+(size_t)((w*4+2)*64+ln)*16); acc=mfma16(Ah,B,acc); acc=mfma16(Al,B,acc);
  B=*(const vi4*)(buf+(size_t)((w*4+3)*64+ln)*16); acc=mfma16(Ah,B,acc);
}

struct Ptrs {
  const float* ts; const float* gts;
  const unsigned short* Wm; const unsigned short* Wa;
  const float* Qb; const float* Fbp; const float* f1b;
  const float* m1w; const float* m1b; const float* m2w; const float* m2b;
  float* cg; float* out;
};

__global__ __launch_bounds__(NTHR,4) void fused_kernel(Ptrs P){
  __shared__ __align__(16) char  h9[45056];     // 11 slots x 4KB (0=h_tsa,1..8=nodes,9=h_ts,10=q/hbar)
  __shared__ __align__(16) char  ring[32768];   // 2 x 16KB chunk ring
  __shared__ __align__(16) float attn_s[1024];  // qk fp32 / p

  const int tid=threadIdx.x;
  const int r0=blockIdx.x*R_WG;
  const int w=tid>>6, ln=tid&63;
  const bool w4=(w<4);
  const int arow=ln&15, kb=ln>>4, qq=ln&3;
  const int rowN=(kb<<2)|qq;                               // nonlin row
  const int u0 = (w>>1)*16 + ((ln>>2)&3)*4 + (w&1)*2;      // nonlin u-pair base (even)
  const int colw = (w&3)*16 + arow;                        // attn C col (waves 0-3)
  const int crow0 = kb<<2;
  char* buf0=ring; char* buf1=ring+16384;
  const char* Wmb=(const char*)P.Wm;
  const char* Wab=(const char*)P.Wa;
  #define WCH(l_,c_) (Wmb + (((size_t)(l_)*12+(size_t)t)*6+(size_t)(c_))*16384)

  float bQ =P.Qb [colw];
  float bF =P.Fbp[colw];
  float bf1v=P.f1b[colw];
  asm volatile("s_waitcnt vmcnt(0)" ::: "memory");   // keep bias loads out of the ledger

  for(int i=tid;i<45056/16;i+=NTHR) ((vi4*)h9)[i]=(vi4){0,0,0,0};

  vf4 xa_c,xb_c,xa_n,xb_n;
  vf2 cv_c,cv_n;

  // prologue FIFO: [c0:2, c1:2, x:2, cv:1] = 7
  {
    int t=0;
    issue2(WCH(0,0), buf0, w, ln);
    issue2(WCH(0,1), buf1, w, ln);
  }
  { // x loads uniform across all threads (kb>=2 lanes load kb&1 data, unused)
    const float* xs=P.ts+(size_t)(r0+arow)*192 + (kb&1)*8;
    xa_c=*(const vf4*)xs; xb_c=*(const vf4*)(xs+4);
  }
  cv_c=*(const vf2*)(P.cg + ((size_t)0*8192 + r0+rowN)*64 + u0);
  BAR();   // h9 zeros visible; vm stays outstanding

  for(int t=0;t<T_SZ;t++){
    // ============ 9 LSTMs: 6 chunk-phases each, ledger {5,2,2,2,2,5} ============
    #pragma unroll 1
    for(int l=0;l<9;l++){
      const int slotA=(l==0)?0:l;
      vf4 a0={0,0,0,0},a1={0,0,0,0};
      vi4 Ah,Al;
      // c0
      WAITV(5);
      a_read(h9,slotA,0,arow,kb,Ah,Al);
      lstm_hi2(a0,a1,Ah,Al,buf0,w,ln);
      LWAIT();
      issue2(WCH(l,2),buf0,w,ln);
      // c1
      WAITV(2);
      lstm_lo2(a0,a1,Ah,buf1,w,ln);
      LWAIT();
      issue2(WCH(l,3),buf1,w,ln);
      // c2
      WAITV(2);
      a_read(h9,slotA,1,arow,kb,Ah,Al);
      lstm_hi2(a0,a1,Ah,Al,buf0,w,ln);
      LWAIT();
      issue2(WCH(l,4),buf0,w,ln);
      // c3
      WAITV(2);
      lstm_lo2(a0,a1,Ah,buf1,w,ln);
      LWAIT();
      issue2(WCH(l,5),buf1,w,ln);
      // c4 (x | bias | 0 in A)
      WAITV(2);
      {
        vi4 xh,xl;
        if(kb<2){
          float xf[8]={xa_c[0],xa_c[1],xa_c[2],xa_c[3],xb_c[0],xb_c[1],xb_c[2],xb_c[3]};
          unsigned short hh[8],llo[8];
          #pragma unroll
          for(int j=0;j<8;j++){ hh[j]=bf_hi(xf[j]); llo[j]=bf_hi(xf[j]-bf_f(hh[j])); }
          xh=(vi4){(int)((unsigned)hh[0]|((unsigned)hh[1]<<16)),(int)((unsigned)hh[2]|((unsigned)hh[3]<<16)),
                   (int)((unsigned)hh[4]|((unsigned)hh[5]<<16)),(int)((unsigned)hh[6]|((unsigned)hh[7]<<16))};
          xl=(vi4){(int)((unsigned)llo[0]|((unsigned)llo[1]<<16)),(int)((unsigned)llo[2]|((unsigned)llo[3]<<16)),
                   (int)((unsigned)llo[4]|((unsigned)llo[5]<<16)),(int)((unsigned)llo[6]|((unsigned)llo[7]<<16))};
        } else if(kb==2){ xh=(vi4){0x3F80,0,0,0}; xl=(vi4){0,0,0,0}; }
        else            { xh=(vi4){0,0,0,0};     xl=(vi4){0,0,0,0}; }
        Ah=xh; Al=xl;
      }
      lstm_hi2(a0,a1,Ah,Al,buf0,w,ln);
      if(l<8){
        LWAIT();
        issue2(WCH(l+1,0),buf0,w,ln);
        { // next x (node l): uniform loads
          const float* xs=P.gts+(size_t)(r0+arow)*1536 + (size_t)l*192 + (size_t)t*16 + (kb&1)*8;
          xa_n=*(const vf4*)xs; xb_n=*(const vf4*)(xs+4);
        }
        cv_n=*(const vf2*)(P.cg + ((size_t)(l+1)*8192 + r0+rowN)*64 + u0);
      } else {
        BAR();                      // all c4(buf0) reads done before cross-wave Qw DMA
        if(w4) issue4(Wab+0*16384,buf0,w,ln);     // Qwc
      }
      // c5
      if(l<8){ WAITV(5); } else { if(w4){ WAITV(4);} else { WAITV(0);} }
      lstm_lo2(a0,a1,Ah,buf1,w,ln);
      BAR();   // all A/B reads done before nonlin writes slot l / cross-wave Kw DMA
      if(l<8){ issue2(WCH(l+1,1),buf1,w,ln); }
      else   { if(w4) issue4(Wab+1*16384,buf1,w,ln); }   // Kwc
      // nonlin: quad-transpose; thread owns (rowN, u0) and (rowN, u0+1)
      {
        float hh2[2],cc2[2];
        float cold[2]={ (t==0)?0.f:cv_c[0], (t==0)?0.f:cv_c[1] };
        vf4 accs[2]={a0,a1};
        #pragma unroll
        for(int nt=0;nt<2;nt++){
          vf4 av=accs[nt];
          float v0=av[0],v1=av[1],v2=av[2],v3=av[3];
          auto sel=[&](int e)->float{ return e==0?v0:(e==1?v1:(e==2?v2:v3)); };
          float own=sel(qq);
          float r1=__shfl_xor(sel(qq^1),1);
          float r2=__shfl_xor(sel(qq^2),2);
          float r3=__shfl_xor(sel(qq^3),3);
          float gi=(qq==0)?own:((qq==1)?r1:((qq==2)?r2:r3));
          float gf=(qq==1)?own:((qq==0)?r1:((qq==3)?r2:r3));
          float gg=(qq==2)?own:((qq==3)?r1:((qq==0)?r2:r3));
          float go=(qq==3)?own:((qq==2)?r1:((qq==1)?r2:r3));
          float iv=sigm(gi),fv=sigm(gf),gv=tanh_f(gg),ov=sigm(go);
          float c2=fv*cold[nt]+iv*gv;
          cc2[nt]=c2; hh2[nt]=ov*tanh_f(c2);
        }
        *(vf2*)(P.cg + ((size_t)l*8192 + r0+rowN)*64 + u0) = (vf2){cc2[0],cc2[1]};
        h9_w2(h9,(l==0)?9:l,rowN,u0,hh2[0],hh2[1]);
      }
      xa_c=xa_n; xb_c=xb_n; cv_c=cv_n;
    }

    // ============ attention / fusion (MFMA on waves 0-3; ledger {4,...}) ============
    vf4 acA, facc;
    // phQ: q = h_ts@Qw.T + Qb -> slot10
    if(w4){
      WAITV(4);
      acA=(vf4){bQ,bQ,bQ,bQ};
      agemm(acA,h9,9,buf0,w,ln);
      LWAIT();
      issue4(Wab+2*16384,buf0,w,ln);              // VFc
      #pragma unroll
      for(int rg=0;rg<4;rg++) h9_w1(h9,10,crow0+rg,colw,acA[rg]);
    }
    BAR();
    // phK: qk = q@(0.125*Kw) -> attn_s fp32
    if(w4){
      WAITV(4);
      acA=(vf4){0,0,0,0};
      agemm(acA,h9,10,buf1,w,ln);
      LWAIT();
      issue4(Wab+3*16384,buf1,w,ln);              // FBc
      #pragma unroll
      for(int rg=0;rg<4;rg++) attn_s[(crow0+rg)*64+colw]=acA[rg];
    }
    BAR();
    // phS: scores + softmax (two-phase p store)
    float pval=0.f;
    if(tid<128){
      int rr=tid>>3, nn=tid&7;
      const char* hp=h9+(nn+1)*4096;
      float s=0.f;
      #pragma unroll
      for(int kbl=0;kbl<8;kbl++){
        int blk=kbl^(rr&7);
        const char* pp=hp+(rr*8+blk)*16;
        vi4 hv=*(const vi4*)pp;
        vi4 lv=*(const vi4*)(pp+2048);
        const float* qkp=attn_s+rr*64+kbl*8;
        #pragma unroll
        for(int e=0;e<4;e++){
          unsigned hw=((const unsigned*)&hv)[e], lw=((const unsigned*)&lv)[e];
          float w0=__uint_as_float(hw<<16)+__uint_as_float(lw<<16);
          float w1=__uint_as_float(hw&0xffff0000u)+__uint_as_float(lw&0xffff0000u);
          s+=w0*qkp[e*2]+w1*qkp[e*2+1];
        }
      }
      float mx=s;
      mx=fmaxf(mx,__shfl_xor(mx,1));
      mx=fmaxf(mx,__shfl_xor(mx,2));
      mx=fmaxf(mx,__shfl_xor(mx,4));
      float e=__expf(s-mx);
      float sm=e;
      sm+=__shfl_xor(sm,1); sm+=__shfl_xor(sm,2); sm+=__shfl_xor(sm,4);
      pval=e/sm;
    }
    BAR();
    if(tid<128) attn_s[tid]=pval;    // p[row][n]
    BAR();
    // phH: hbar -> slot10 (all 8 waves, 2 rows each)
    {
      int uu=tid&63, rbh=w*2;
      #pragma unroll
      for(int ri=0;ri<2;ri++){
        int row=rbh+ri;
        float sa=0.f;
        #pragma unroll
        for(int n=0;n<8;n++) sa+=attn_s[row*8+n]*h9_rd(h9,n+1,row,uu);
        h9_w1(h9,10,row,uu,sa);
      }
    }
    BAR();
    // phC: VF*hbar ; phB: + FB*h_ts -> h_tsa slot0
    if(w4){
      WAITV(4);
      acA=(vf4){bF,bF,bF,bF};
      agemm(acA,h9,10,buf0,w,ln);
      LWAIT();
      issue4(Wab+4*16384,buf0,w,ln);              // F1Bc
      WAITV(4);
      agemm(acA,h9,9,buf1,w,ln);
      LWAIT();
      issue4(Wab+5*16384,buf1,w,ln);              // F1Ac
      #pragma unroll
      for(int rg=0;rg<4;rg++) h9_w1(h9,0,crow0+rg,colw,fmaxf(acA[rg],0.f));
    }
    if(t==T_SZ-1) break;
    // phF: f_ts (regs, waves 0-3)
    if(w4){
      WAITV(4);
      facc=(vf4){bf1v,bf1v,bf1v,bf1v};
      agemm(facc,h9,9,buf0,w,ln);
    }
    BAR();                                        // buf0 F1B reads done before l0c0 DMA
    issue2(Wmb + (((size_t)0*12+(size_t)(t+1))*6+0)*16384, buf0,w,ln);   // l0c0(t+1), all waves
    // phX: fusion (waves 0-3), then all-wave staging for t+1
    if(w4){
      WAITV(2);
      vf4 g1=facc,g2=facc,g3=facc,g4=facc,g5=facc,g6=facc,g7=facc,g8=facc;
      agemm(g1,h9,1,buf1,w,ln); agemm(g2,h9,2,buf1,w,ln);
      agemm(g3,h9,3,buf1,w,ln); agemm(g4,h9,4,buf1,w,ln);
      agemm(g5,h9,5,buf1,w,ln); agemm(g6,h9,6,buf1,w,ln);
      agemm(g7,h9,7,buf1,w,ln); agemm(g8,h9,8,buf1,w,ln);
      BAR();   // all slot & buf1 reads done before overwrite / l0c1 DMA
      #pragma unroll
      for(int rg=0;rg<4;rg++){
        h9_w1(h9,1,crow0+rg,colw,fmaxf(g1[rg],0.f));
        h9_w1(h9,2,crow0+rg,colw,fmaxf(g2[rg],0.f));
        h9_w1(h9,3,crow0+rg,colw,fmaxf(g3[rg],0.f));
        h9_w1(h9,4,crow0+rg,colw,fmaxf(g4[rg],0.f));
        h9_w1(h9,5,crow0+rg,colw,fmaxf(g5[rg],0.f));
        h9_w1(h9,6,crow0+rg,colw,fmaxf(g6[rg],0.f));
        h9_w1(h9,7,crow0+rg,colw,fmaxf(g7[rg],0.f));
        h9_w1(h9,8,crow0+rg,colw,fmaxf(g8[rg],0.f));
      }
    } else {
      BAR();   // matching barrier for waves 4-7
    }
    issue2(Wmb + (((size_t)0*12+(size_t)(t+1))*6+1)*16384, buf1,w,ln);   // l0c1(t+1)
    { // x(t+1) uniform
      const float* xs=P.ts+(size_t)(r0+arow)*192 + (size_t)(t+1)*16 + (kb&1)*8;
      xa_n=*(const vf4*)xs; xb_n=*(const vf4*)(xs+4);
    }
    cv_n=*(const vf2*)(P.cg + ((size_t)0*8192 + r0+rowN)*64 + u0);
    BAR();   // fusion writes visible for next t
    xa_c=xa_n; xb_c=xb_n; cv_c=cv_n;
  }

  // ============ final MLP from slot0 (h_tsa) ============
  WAITV(0);
  BAR();
  {
    int rr=tid>>5, ii=tid&31;
    float h=P.m1b[ii];
    for(int k=0;k<64;k++) h+=h9_rd(h9,0,rr,k)*P.m1w[(size_t)ii*64+k];
    attn_s[rr*32+ii]=fmaxf(h,0.f);
  }
  BAR();
  if(tid<R_WG){
    float s=P.m2b[0];
    for(int i=0;i<32;i++) s+=attn_s[tid*32+i]*P.m2w[i];
    P.out[r0+tid]=s;
  }
  #undef WCH
}

// ---- prep: LSTM weight chunks, split-bf16, frag layout; bias folded at k=80 ----
__global__ void prep_wm(const float* eW, const float* eU, const float* e2W, const float* e2U,
                        const float* emb_w, const float* eb_ih, const float* eb_hh,
                        const float* e2b_ih, const float* e2b_hh, const float* emb_b,
                        unsigned short* dst){
  int id=blockIdx.x*256+threadIdx.x;
  if(id>=108*3*16*64) return;
  int lane=id&63;
  int q=id>>6;
  int wnt=q&15;
  int q2=q>>4;
  int ks=q2%3;
  int lt=q2/3;
  int LL=lt/12, t=lt%12;
  int c15=lane&15;
  int u=(wnt>>2)*16+(c15>>2)*4+(wnt&3);
  int gt=c15&3;
  int jg=gt*64+u;
  const float* Whh=(LL==0)? eU+((size_t)t*256+jg)*64 : e2U+(((size_t)(LL-1)*12+t)*256+jg)*64;
  const float* Wih=(LL==0)? eW+((size_t)t*256+jg)*32 : e2W+(((size_t)(LL-1)*12+t)*256+jg)*32;
  float bsum;
  {
    float bi=(LL==0)? eb_ih[t*256+jg] : e2b_ih[((LL-1)*12+t)*256+jg];
    float bh=(LL==0)? eb_hh[t*256+jg] : e2b_hh[((LL-1)*12+t)*256+jg];
    float s=bi+bh;
    for(int i=0;i<32;i++) s+=Wih[i]*emb_b[i];
    bsum=s;
  }
  #pragma unroll
  for(int j=0;j<8;j++){
    int k=ks*32+(lane>>4)*8+j;
    float v;
    if(k<64) v=Whh[k];
    else if(k<80){
      int kx=k-64; float s=0.f;
      for(int i=0;i<32;i++) s+=Wih[i]*emb_w[i*16+kx];
      v=s;
    } else if(k==80) v=bsum;
    else v=0.f;
    unsigned short hi=bf_hi(v), lo=bf_hi(v-bf_f(hi));
    size_t base=((size_t)lt*6+ks*2)*8192 + ((size_t)wnt*64+lane)*8 + j;
    dst[base]=hi;
    dst[base+8192]=lo;
  }
}

// ---- prep: 6 attention/fusion chunks [colblk][ks][split][lane][8], + Fbp ----
__global__ void prep_attw(const float* Qw, const float* Kw, const float* Vw, const float* Vb,
                          const float* Fw, const float* Fb, const float* f1w,
                          unsigned short* dst, float* Fbp){
  int id=blockIdx.x*256+threadIdx.x;
  if(id<6144){
    int cidx=id>>10;
    int rem=id&1023;
    int block=rem>>6;
    int lane=rem&63;
    int ks=(block>>1)&1, s=block&1;
    int col=(block>>2)*16+(lane&15);
    #pragma unroll
    for(int j=0;j<8;j++){
      int k=ks*32+(lane>>4)*8+j;
      float v;
      if(cidx==0) v=Qw[col*64+k];
      else if(cidx==1) v=Kw[k*64+col]*0.125f;
      else if(cidx==2){ float sv=0.f; for(int m=0;m<64;m++) sv+=Fw[col*128+m]*Vw[m*64+k]; v=sv; }
      else if(cidx==3) v=Fw[col*128+64+k];
      else if(cidx==4) v=f1w[col*128+64+k];
      else             v=f1w[col*128+k];
      unsigned short hi=bf_hi(v);
      dst[(size_t)cidx*8192 + ((size_t)block*64+lane)*8 + j] = (s==0)? hi : bf_hi(v-bf_f(hi));
    }
  } else if(id<6144+64){
    int u=id-6144;
    float s=Fb[u];
    for(int m=0;m<64;m++) s+=Fw[u*128+m]*Vb[m];
    Fbp[u]=s;
  }
}

extern "C" void kernel_launch(void* const* d_in, const int* in_sizes, int n_in,
                              void* d_out, int out_size, void* d_ws, size_t ws_size,
                              hipStream_t stream){
  const float* ts      =(const float*)d_in[0];
  const float* gts     =(const float*)d_in[1];
  const float* emb_w   =(const float*)d_in[2];
  const float* emb_b   =(const float*)d_in[3];
  const float* attQ_w  =(const float*)d_in[4];
  const float* attQ_b  =(const float*)d_in[5];
  const float* attK_w  =(const float*)d_in[6];
  // d_in[7] attK_b: softmax-invariant, unused
  const float* attV_w  =(const float*)d_in[8];
  const float* attV_b  =(const float*)d_in[9];
  const float* attF_w  =(const float*)d_in[10];
  const float* attF_b  =(const float*)d_in[11];
  const float* fuse1_w =(const float*)d_in[12];
  const float* fuse1_b =(const float*)d_in[13];
  const float* enc_Wih =(const float*)d_in[14];
  const float* enc_Whh =(const float*)d_in[15];
  const float* enc_bih =(const float*)d_in[16];
  const float* enc_bhh =(const float*)d_in[17];
  const float* enc2_Wih=(const float*)d_in[18];
  const float* enc2_Whh=(const float*)d_in[19];
  const float* enc2_bih=(const float*)d_in[20];
  const float* enc2_bhh=(const float*)d_in[21];
  const float* mlp1_w  =(const float*)d_in[22];
  const float* mlp1_b  =(const float*)d_in[23];
  const float* mlp2_w  =(const float*)d_in[24];
  const float* mlp2_b  =(const float*)d_in[25];

  char* ws=(char*)d_ws;
  size_t off=0;
  unsigned short* Wm=(unsigned short*)(ws+off); off+=(size_t)108*6*8192*2;
  unsigned short* Wa=(unsigned short*)(ws+off); off+=(size_t)6*8192*2;
  float* Fbp=(float*)(ws+off); off+=64*4;
  float* cg =(float*)(ws+off); off+=(size_t)9*8192*64*4;

  prep_wm<<<(108*3*16*64+255)/256,256,0,stream>>>(enc_Wih,enc_Whh,enc2_Wih,enc2_Whh,emb_w,
                                                  enc_bih,enc_bhh,enc2_bih,enc2_bhh,emb_b,Wm);
  prep_attw<<<25,256,0,stream>>>(attQ_w,attK_w,attV_w,attV_b,attF_w,attF_b,fuse1_w,Wa,Fbp);

  Ptrs P;
  P.ts=ts; P.gts=gts; P.Wm=Wm; P.Wa=Wa;
  P.Qb=attQ_b; P.Fbp=Fbp; P.f1b=fuse1_b;
  P.m1w=mlp1_w; P.m1b=mlp1_b; P.m2w=mlp2_w; P.m2b=mlp2_b;
  P.cg=cg; P.out=(float*)d_out;

  fused_kernel<<<NWG,NTHR,0,stream>>>(P);
}